// Round 10
// baseline (540.345 us; speedup 1.0000x reference)
//
#include <hip/hip_runtime.h>

typedef __attribute__((ext_vector_type(4))) float f32x4;
typedef __attribute__((ext_vector_type(8))) short bf16x8;
typedef unsigned short u16;

#define DEVINL static __device__ __forceinline__

DEVINL float b2f(u16 u) { union { unsigned int i; float f; } x; x.i = ((unsigned int)u) << 16; return x.f; }
DEVINL u16 f2bf(float f) {
  union { float f; unsigned int i; } x; x.f = f;
  unsigned int r = x.i + 0x7fffu + ((x.i >> 16) & 1u);
  return (u16)(r >> 16);
}
DEVINL float ldin(const void* p, long i, int f) {
  return f ? ((const float*)p)[i] : b2f(((const u16*)p)[i]);
}
DEVINL void ld4bf(const u16* p, float* o) {
  ushort4 v = *(const ushort4*)p;
  o[0] = b2f(v.x); o[1] = b2f(v.y); o[2] = b2f(v.z); o[3] = b2f(v.w);
}
DEVINL void st4out(void* out, size_t idx, const float* v, int f) {
  if (f) {
    float4 t; t.x = v[0]; t.y = v[1]; t.z = v[2]; t.w = v[3];
    *(float4*)((float*)out + idx) = t;
  } else {
    ushort4 t; t.x = f2bf(v[0]); t.y = f2bf(v[1]); t.z = f2bf(v[2]); t.w = f2bf(v[3]);
    *(ushort4*)((u16*)out + idx) = t;
  }
}
DEVINL void cv8(const void* s, long i, int f, u16* d) {
  if (f) {
    const float4 a = *(const float4*)((const float*)s + i);
    const float4 b = *(const float4*)((const float*)s + i + 4);
    ushort4 lo, hi;
    lo.x = f2bf(a.x); lo.y = f2bf(a.y); lo.z = f2bf(a.z); lo.w = f2bf(a.w);
    hi.x = f2bf(b.x); hi.y = f2bf(b.y); hi.z = f2bf(b.z); hi.w = f2bf(b.w);
    *(ushort4*)d = lo; *(ushort4*)(d + 4) = hi;
  } else {
    const ushort4 a = *(const ushort4*)((const u16*)s + i);
    const ushort4 b = *(const ushort4*)((const u16*)s + i + 4);
    *(ushort4*)d = a; *(ushort4*)(d + 4) = b;
  }
}

// ---------------- workspace layout (bytes); all GEMM K padded to 512 ----------------
static constexpr size_t OFF_FLAG = 0;
static constexpr size_t OFF_WIH  = 1024;        // bf16 [8][1536][512] (k>=400 zero)
static constexpr size_t OFF_WHH  = 12583936;    // bf16 [8][1536][512]
static constexpr size_t OFF_QVW  = 25166848;    // bf16 [8][768][512]
static constexpr size_t OFF_OUTW = 31458304;    // bf16 [8][512][512] (k>=400 zero)
static constexpr size_t OFF_VALW = 35652608;    // bf16 [512][512]
static constexpr size_t OFF_VBP  = 36176896;    // bf16 [512]
static constexpr size_t OFF_BIH  = 36177920;    // bf16 [8][1536]
static constexpr size_t OFF_BHH  = 36202496;    // bf16 [8][1536]
static constexpr size_t OFF_RNG  = 36227072;    // bf16 [8][512]
static constexpr size_t OFF_RNB  = 36235264;    // bf16 [8][512]
static constexpr size_t OFF_LNG  = 36243456;    // bf16 [512]
static constexpr size_t OFF_LNB  = 36244480;    // bf16 [512]
static constexpr size_t OFF_HMF  = 36245504;    // f32  [4096]
static constexpr size_t OFF_XB   = 36261888;    // bf16 [4096][512]
static constexpr size_t OFF_HSB  = 40456192;    // bf16 [4096][8][512] (straight hs copy)
static constexpr size_t OFF_KL   = 74010624;    // f32  [4096][64]
static constexpr size_t OFF_VL   = 75059200;    // f32  [4096][512]
static constexpr size_t OFF_QL   = 83447808;    // f32  [4096][512]
static constexpr size_t OFF_MASK = 91836416;    // f32  [4096][8]
static constexpr size_t OFF_HB   = 91967488;    // bf16 [8][4096][512]
static constexpr size_t OFF_R    = 125521920;   // reusable: INP[8][4096][512] + GI/GH | QVC/CTX/CTX2

// ---------------- dtype detect: even-u16 plausibility ----------------
__global__ __launch_bounds__(256) void detect_kernel(const u16* __restrict__ hs_u, int* __restrict__ flag) {
  __shared__ int cnt;
  if (threadIdx.x == 0) cnt = 0;
  __syncthreads();
  int ok = 0;
  for (int i = threadIdx.x; i < 1024; i += 256) {
    const float v = fabsf(b2f(hs_u[2 * i]));
    if (v > 9.094947e-13f && v < 1.0995116e12f) ok++;   // 2^-40 .. 2^40
  }
  atomicAdd(&cnt, ok);
  __syncthreads();
  if (threadIdx.x == 0) flag[0] = (cnt >= 921) ? 0 : 1;  // bf16(0) / fp32(1)
}

// ---------------- vectorized flat convert/pad (8 elems/thread) ----------------
__global__ __launch_bounds__(256) void flatconv_kernel(
    const void* __restrict__ W_ih, const void* __restrict__ W_hh, const void* __restrict__ x,
    const void* __restrict__ hs, const void* __restrict__ value_b, const void* __restrict__ b_ih,
    const void* __restrict__ b_hh, const void* __restrict__ rnn_g, const void* __restrict__ rnn_b,
    const void* __restrict__ ln_g, const void* __restrict__ ln_b, const void* __restrict__ h_masks,
    const int* __restrict__ flagp,
    u16* __restrict__ WIH, u16* __restrict__ WHH, u16* __restrict__ XB, u16* __restrict__ HSB,
    u16* __restrict__ VBP, u16* __restrict__ BIH, u16* __restrict__ BHH,
    u16* __restrict__ RNG, u16* __restrict__ RNB, u16* __restrict__ LNG, u16* __restrict__ LNB,
    float* __restrict__ HMF)
{
  const int f = flagp[0];
  long t = (long)blockIdx.x * 256 + threadIdx.x;
  if (t < 786432L) {                         // WIH [r=u*1536][512], pad k>=400
    const long r = t >> 6; const int k = (int)(t & 63) * 8;
    u16* d = WIH + r * 512 + k;
    if (k < 400) cv8(W_ih, r * 400 + k, f, d);
    else { ushort4 z{0,0,0,0}; *(ushort4*)d = z; *(ushort4*)(d + 4) = z; }
    return;
  }
  t -= 786432L;
  if (t < 786432L) { cv8(W_hh, t * 8, f, WHH + t * 8); return; }
  t -= 786432L;
  if (t < 262144L) { cv8(x, t * 8, f, XB + t * 8); return; }
  t -= 262144L;
  if (t < 2097152L) { cv8(hs, t * 8, f, HSB + t * 8); return; }
  t -= 2097152L;
  if (t < 512L) { VBP[t] = (t < 400) ? f2bf(ldin(value_b, t, f)) : (u16)0; return; }
  t -= 512L;
  if (t < 12288L) { BIH[t] = f2bf(ldin(b_ih, t, f)); return; }
  t -= 12288L;
  if (t < 12288L) { BHH[t] = f2bf(ldin(b_hh, t, f)); return; }
  t -= 12288L;
  if (t < 4096L) { RNG[t] = f2bf(ldin(rnn_g, t, f)); return; }
  t -= 4096L;
  if (t < 4096L) { RNB[t] = f2bf(ldin(rnn_b, t, f)); return; }
  t -= 4096L;
  if (t < 512L) { LNG[t] = f2bf(ldin(ln_g, t, f)); return; }
  t -= 512L;
  if (t < 512L) { LNB[t] = f2bf(ldin(ln_b, t, f)); return; }
  t -= 512L;
  if (t < 4096L) { HMF[t] = ldin(h_masks, t, f); return; }
}

// ---------------- LDS-tiled transpose: dst[z][n][k](bf16,[*][Kp]) = src[z][k][n], zero-pad ----------------
__global__ __launch_bounds__(256) void transpose_kernel(
    const void* __restrict__ src, const int* __restrict__ flagp, u16* __restrict__ dst,
    int K, int N, int Kp, long srcZ, long dstZ)
{
  const int f = flagp[0];
  __shared__ float t[64][65];
  const int k0 = blockIdx.x * 64, n0 = blockIdx.y * 64, z = blockIdx.z;
  const int tid = threadIdx.x;
  const int lk = tid >> 4;
  const int ln4 = (tid & 15) * 4;
#pragma unroll
  for (int p = 0; p < 4; ++p) {
    const int k = k0 + lk + p * 16;
    float v[4] = {0.f, 0.f, 0.f, 0.f};
    if (k < K) {
      const long base = srcZ * z + (long)k * N + n0 + ln4;
#pragma unroll
      for (int j = 0; j < 4; ++j)
        if (n0 + ln4 + j < N) v[j] = ldin(src, base + j, f);
    }
    t[lk + p * 16][ln4 + 0] = v[0]; t[lk + p * 16][ln4 + 1] = v[1];
    t[lk + p * 16][ln4 + 2] = v[2]; t[lk + p * 16][ln4 + 3] = v[3];
  }
  __syncthreads();
#pragma unroll
  for (int p = 0; p < 4; ++p) {
    const int n = n0 + lk + p * 16;
    ushort4 o;
    o.x = f2bf(t[ln4 + 0][lk + p * 16]);
    o.y = f2bf(t[ln4 + 1][lk + p * 16]);
    o.z = f2bf(t[ln4 + 2][lk + p * 16]);
    o.w = f2bf(t[ln4 + 3][lk + p * 16]);
    *(ushort4*)&dst[dstZ * z + (long)n * Kp + k0 + ln4] = o;
  }
}

// ---------------- 8-phase 256x256 MFMA NT GEMM, K=512 (T1+T2+T3+T4+T5, fa-reuse) ----------------
// Operand-swapped MFMA: mfma(fb, fa) -> D[n-frag][m-frag], so reg axis t walks 4 consecutive
// COLUMNS of C -> ushort4/float4 stores (32 insts vs 128). Lanes {l,l+16,l+32,l+48} cover
// one contiguous 32B row segment. K-loop identical to round 9 (passing).
template<int OUT_BF16, int HAS_BIAS>
__global__ __launch_bounds__(512, 2) void gemm8_kernel(
    const u16* __restrict__ A, const u16* __restrict__ W, void* __restrict__ Cp,
    const u16* __restrict__ bias, int ldaE, long Az, long Wz, long Cz, int Bz, int ldc)
{
  __shared__ u16 lds[65536];   // 128 KiB
  const int tid = threadIdx.x;
  const int w = tid >> 6, l = tid & 63;
  const int wr = w >> 2, wc = w & 3;
  const int lr = l & 15, kg = l >> 4;
  const int l3 = l >> 3;
  const int l7ks = ((l & 7) ^ l3) * 8;       // T2 inverse-swizzled source col (elems)
  const int lswz = (lr & 7) << 3;            // T2 read swizzle (elems)

  // T1: bijective XCD swizzle (requires nwg % 8 == 0), by-fastest for A-panel L2 reuse
  int bx, by, bz;
  {
    const int gx = gridDim.x, gy = gridDim.y;
    const int nwg = gx * gy * (int)gridDim.z;
    int flat = (int)blockIdx.x + gx * ((int)blockIdx.y + gy * (int)blockIdx.z);
    flat = (flat & 7) * (nwg >> 3) + (flat >> 3);
    by = flat % gy; const int tmp = flat / gy;
    bx = tmp % gx; bz = tmp / gx;
  }
  const int m0 = bx * 256, n0 = by * 256, z = bz;
  const u16* Au = A + (size_t)z * Az;
  const u16* Wu = W + (size_t)z * Wz;

  f32x4 acc[8][4];
#pragma unroll
  for (int i = 0; i < 8; ++i)
#pragma unroll
    for (int j = 0; j < 4; ++j) acc[i][j] = (f32x4){0.f, 0.f, 0.f, 0.f};

  bf16x8 fa[2][4], fb[2][2];

#define GL8(srcp, dstoff) __builtin_amdgcn_global_load_lds( \
    (const __attribute__((address_space(1))) void*)(srcp), \
    (__attribute__((address_space(3))) void*)((char*)lds + 2 * (dstoff)), 16, 0, 0)

#define STAGE_A8(t, mh, slot) do { \
  _Pragma("unroll") for (int c_ = 0; c_ < 2; ++c_) { \
    const int row0_ = (mh) * 64 + w * 8 + c_ * 128; \
    GL8(Au + (size_t)(m0 + row0_ + l3) * ldaE + (t) * 64 + l7ks, (slot) * 16384 + row0_ * 64); \
  } } while (0)

#define STAGE_B8(t, nh, slot) do { \
  _Pragma("unroll") for (int c_ = 0; c_ < 2; ++c_) { \
    const int rq0_ = w * 8 + c_ * 64; \
    const int row0_ = ((rq0_ >> 5) << 6) + (nh) * 32 + (rq0_ & 31); \
    GL8(Wu + (size_t)(n0 + row0_ + l3) * 512 + (t) * 64 + l7ks, 32768 + (slot) * 16384 + row0_ * 64); \
  } } while (0)

#define VMW4 asm volatile("s_waitcnt vmcnt(4)" ::: "memory")

#define LOAD_FA(sl, mh) do { \
  _Pragma("unroll") for (int kk = 0; kk < 2; ++kk) \
    _Pragma("unroll") for (int mq = 0; mq < 4; ++mq) \
      fa[kk][mq] = *(const bf16x8*)&lds[(sl) * 16384 + (wr * 128 + (mh) * 64 + mq * 16 + lr) * 64 + ((kk * 32 + kg * 8) ^ lswz)]; \
} while (0)

#define LOAD_FB(sl, nh) do { \
  _Pragma("unroll") for (int kk = 0; kk < 2; ++kk) \
    _Pragma("unroll") for (int nq = 0; nq < 2; ++nq) \
      fb[kk][nq] = *(const bf16x8*)&lds[32768 + (sl) * 16384 + (wc * 64 + (nh) * 32 + nq * 16 + lr) * 64 + ((kk * 32 + kg * 8) ^ lswz)]; \
} while (0)

#define PHASE_MM(mh, nh, STG, VMW) do { \
  STG; \
  asm volatile("" ::: "memory"); \
  __builtin_amdgcn_s_barrier(); \
  __builtin_amdgcn_s_setprio(1); \
  _Pragma("unroll") for (int kk = 0; kk < 2; ++kk) \
    _Pragma("unroll") for (int mq = 0; mq < 4; ++mq) \
      _Pragma("unroll") for (int nq = 0; nq < 2; ++nq) \
        acc[(mh) * 4 + mq][(nh) * 2 + nq] = __builtin_amdgcn_mfma_f32_16x16x32_bf16( \
            fb[kk][nq], fa[kk][mq], acc[(mh) * 4 + mq][(nh) * 2 + nq], 0, 0, 0); \
  __builtin_amdgcn_s_setprio(0); \
  VMW; \
  asm volatile("" ::: "memory"); \
  __builtin_amdgcn_s_barrier(); \
} while (0)

  // prologue: slot0 full (tile 0) + slot1 A0,B0 (tile 1); keep slot1's 4 in flight
  STAGE_A8(0, 0, 0); STAGE_A8(0, 1, 0); STAGE_B8(0, 0, 0); STAGE_B8(0, 1, 0);
  STAGE_A8(1, 0, 1); STAGE_B8(1, 0, 1);
  asm volatile("s_waitcnt vmcnt(4)" ::: "memory");
  __builtin_amdgcn_s_barrier();

  for (int i = 0; i < 4; ++i) {
    const int tB = 2 * i + 1, tC = (2 * i + 2) & 7, tD = (2 * i + 3) & 7;
    LOAD_FA(0, 0); LOAD_FB(0, 0);
    PHASE_MM(0, 0, STAGE_A8(tB, 1, 1), );
    LOAD_FB(0, 1);
    PHASE_MM(0, 1, STAGE_B8(tB, 1, 1), );
    LOAD_FA(0, 1); LOAD_FB(0, 0);
    PHASE_MM(1, 0, STAGE_A8(tC, 0, 0), );
    LOAD_FB(0, 1);
    PHASE_MM(1, 1, STAGE_B8(tC, 0, 0), VMW4);
    LOAD_FA(1, 0); LOAD_FB(1, 0);
    PHASE_MM(0, 0, STAGE_A8(tC, 1, 0), );
    LOAD_FB(1, 1);
    PHASE_MM(0, 1, STAGE_B8(tC, 1, 0), );
    LOAD_FA(1, 1); LOAD_FB(1, 0);
    PHASE_MM(1, 0, STAGE_A8(tD, 0, 1), );
    LOAD_FB(1, 1);
    PHASE_MM(1, 1, STAGE_B8(tD, 0, 1), VMW4);
  }
  asm volatile("s_waitcnt vmcnt(0)" ::: "memory");

  // ---- operand-swapped epilogue: t walks columns -> vector stores ----
  float bvs[4][4];
#pragma unroll
  for (int nf = 0; nf < 4; ++nf) {
    if (HAS_BIAS) ld4bf(bias + (size_t)z * Bz + n0 + wc * 64 + nf * 16 + kg * 4, bvs[nf]);
    else { bvs[nf][0] = bvs[nf][1] = bvs[nf][2] = bvs[nf][3] = 0.f; }
  }
  float* Cf = (float*)Cp;
  u16* Cb = (u16*)Cp;
#pragma unroll
  for (int mf = 0; mf < 8; ++mf) {
    const int gm = m0 + wr * 128 + mf * 16 + lr;
#pragma unroll
    for (int nf = 0; nf < 4; ++nf) {
      const int gn = n0 + wc * 64 + nf * 16 + kg * 4;
      const size_t idx = (size_t)z * Cz + (size_t)gm * ldc + gn;
      if (OUT_BF16) {
        ushort4 o;
        o.x = f2bf(acc[mf][nf][0] + bvs[nf][0]);
        o.y = f2bf(acc[mf][nf][1] + bvs[nf][1]);
        o.z = f2bf(acc[mf][nf][2] + bvs[nf][2]);
        o.w = f2bf(acc[mf][nf][3] + bvs[nf][3]);
        *(ushort4*)(Cb + idx) = o;
      } else {
        float4 o;
        o.x = acc[mf][nf][0] + bvs[nf][0];
        o.y = acc[mf][nf][1] + bvs[nf][1];
        o.z = acc[mf][nf][2] + bvs[nf][2];
        o.w = acc[mf][nf][3] + bvs[nf][3];
        *(float4*)(Cf + idx) = o;
      }
    }
  }
#undef GL8
#undef STAGE_A8
#undef STAGE_B8
#undef VMW4
#undef LOAD_FA
#undef LOAD_FB
#undef PHASE_MM
}

// ---------------- 128x128 MFMA NT GEMM (verified; kept for VL) ----------------
template<int OUT_BF16, int HAS_BIAS>
__global__ __launch_bounds__(256) void gemm_bt_kernel(
    const u16* __restrict__ A, const u16* __restrict__ W, void* __restrict__ Cp,
    const u16* __restrict__ bias, int KP, int ldaE, long Az, long Wz, long Cz, int Bz, int ldc)
{
  __shared__ u16 lA[128 * 64];
  __shared__ u16 lB[128 * 64];
  const int tid = threadIdx.x;
  const int m0 = blockIdx.x * 128, n0 = blockIdx.y * 128, z = blockIdx.z;
  const u16* Au = A + (size_t)z * Az;
  const u16* Wu = W + (size_t)z * Wz;
  const int l = tid & 63, w = tid >> 6;
  const int WM = (w >> 1) * 64, WN = (w & 1) * 64;
  const int lr = l & 15, kg = l >> 4;
  f32x4 acc[4][4];
#pragma unroll
  for (int i = 0; i < 4; ++i)
#pragma unroll
    for (int j = 0; j < 4; ++j) acc[i][j] = (f32x4){0.f, 0.f, 0.f, 0.f};
  const int rowA = tid >> 3;
  const int cb = (tid & 7) * 16;
  const size_t rowBytesA = (size_t)ldaE * 2;
  const size_t rowBytesW = (size_t)KP * 2;
  for (int k0 = 0; k0 < KP; k0 += 64) {
    __syncthreads();
    const char* gA = (const char*)Au + (size_t)(m0 + rowA) * rowBytesA + (size_t)k0 * 2 + cb;
    const char* gB = (const char*)Wu + (size_t)(n0 + rowA) * rowBytesW + (size_t)k0 * 2 + cb;
    char* sA = (char*)lA + (w << 10);
    char* sB = (char*)lB + (w << 10);
#pragma unroll
    for (int c = 0; c < 4; ++c) {
      __builtin_amdgcn_global_load_lds(
          (const __attribute__((address_space(1))) void*)(gA + (size_t)c * 32 * rowBytesA),
          (__attribute__((address_space(3))) void*)(sA + c * 4096), 16, 0, 0);
      __builtin_amdgcn_global_load_lds(
          (const __attribute__((address_space(1))) void*)(gB + (size_t)c * 32 * rowBytesW),
          (__attribute__((address_space(3))) void*)(sB + c * 4096), 16, 0, 0);
    }
    __syncthreads();
#pragma unroll
    for (int kk = 0; kk < 64; kk += 32) {
      bf16x8 af[4], bw[4];
#pragma unroll
      for (int i = 0; i < 4; ++i)
        af[i] = *(const bf16x8*)&lA[(WM + i * 16 + lr) * 64 + kk + kg * 8];
#pragma unroll
      for (int j = 0; j < 4; ++j)
        bw[j] = *(const bf16x8*)&lB[(WN + j * 16 + lr) * 64 + kk + kg * 8];
#pragma unroll
      for (int i = 0; i < 4; ++i)
#pragma unroll
        for (int j = 0; j < 4; ++j)
          acc[i][j] = __builtin_amdgcn_mfma_f32_16x16x32_bf16(af[i], bw[j], acc[i][j], 0, 0, 0);
    }
  }
  float* Cf = (float*)Cp;
  u16* Cb = (u16*)Cp;
#pragma unroll
  for (int i = 0; i < 4; ++i) {
#pragma unroll
    for (int j = 0; j < 4; ++j) {
      const int gc = n0 + WN + j * 16 + lr;
      float bv = 0.f;
      if (HAS_BIAS) bv = b2f(bias[(size_t)z * Bz + gc]);
#pragma unroll
      for (int t = 0; t < 4; ++t) {
        const int gr = m0 + WM + i * 16 + kg * 4 + t;
        const float v = acc[i][j][t] + bv;
        const size_t idx = (size_t)z * Cz + (size_t)gr * ldc + gc;
        if (OUT_BF16) Cb[idx] = f2bf(v); else Cf[idx] = v;
      }
    }
  }
}

// ---------------- exact-dtype fp32 GEMM for the score path ----------------
__global__ __launch_bounds__(256) void gemm_f32bf_kernel(
    const void* __restrict__ A, const void* __restrict__ W, float* __restrict__ C,
    const void* __restrict__ bias, const int* __restrict__ flagp,
    int K, int lda, int ldw, int ldc, long Az, long Wz, long Cz)
{
  const int f32 = flagp[0];
  __shared__ float sA[16][65];
  __shared__ float sW[16][64];
  const int tid = threadIdx.x;
  const int m0 = blockIdx.x * 64, n0 = blockIdx.y * 64, z = blockIdx.z;
  const int tx = tid & 15, ty = tid >> 4;
  const int ar = tid >> 2, ak = (tid & 3) * 4;
  const int wk = tid >> 4, wc = (tid & 15) * 4;
  const size_t abase = (size_t)z * Az, wbase = (size_t)z * Wz;
  float acc[4][4] = {};
  for (int k0 = 0; k0 < K; k0 += 16) {
    __syncthreads();
    float a0, a1, a2, a3, w0, w1, w2, w3;
    const size_t ai = abase + (size_t)(m0 + ar) * lda + k0 + ak;
    const size_t wi = wbase + (size_t)(k0 + wk) * ldw + n0 + wc;
    if (f32) {
      const float4 av = *(const float4*)((const float*)A + ai);
      const float4 wv = *(const float4*)((const float*)W + wi);
      a0 = av.x; a1 = av.y; a2 = av.z; a3 = av.w;
      w0 = wv.x; w1 = wv.y; w2 = wv.z; w3 = wv.w;
    } else {
      const ushort4 av = *(const ushort4*)((const u16*)A + ai);
      const ushort4 wv = *(const ushort4*)((const u16*)W + wi);
      a0 = b2f(av.x); a1 = b2f(av.y); a2 = b2f(av.z); a3 = b2f(av.w);
      w0 = b2f(wv.x); w1 = b2f(wv.y); w2 = b2f(wv.z); w3 = b2f(wv.w);
    }
    sA[ak + 0][ar] = a0; sA[ak + 1][ar] = a1; sA[ak + 2][ar] = a2; sA[ak + 3][ar] = a3;
    sW[wk][wc] = w0; sW[wk][wc + 1] = w1; sW[wk][wc + 2] = w2; sW[wk][wc + 3] = w3;
    __syncthreads();
#pragma unroll
    for (int kk = 0; kk < 16; ++kk) {
      const float a0c = sA[kk][ty * 4 + 0], a1c = sA[kk][ty * 4 + 1];
      const float a2c = sA[kk][ty * 4 + 2], a3c = sA[kk][ty * 4 + 3];
      const float4 bv = *(const float4*)&sW[kk][tx * 4];
      acc[0][0] += a0c * bv.x; acc[0][1] += a0c * bv.y; acc[0][2] += a0c * bv.z; acc[0][3] += a0c * bv.w;
      acc[1][0] += a1c * bv.x; acc[1][1] += a1c * bv.y; acc[1][2] += a1c * bv.z; acc[1][3] += a1c * bv.w;
      acc[2][0] += a2c * bv.x; acc[2][1] += a2c * bv.y; acc[2][2] += a2c * bv.z; acc[2][3] += a2c * bv.w;
      acc[3][0] += a3c * bv.x; acc[3][1] += a3c * bv.y; acc[3][2] += a3c * bv.z; acc[3][3] += a3c * bv.w;
    }
  }
#pragma unroll
  for (int i = 0; i < 4; ++i)
#pragma unroll
    for (int j = 0; j < 4; ++j) {
      const int n = n0 + tx * 4 + j;
      float v = acc[i][j];
      if (bias) v += ldin(bias, n, f32);
      C[(size_t)z * Cz + (size_t)(m0 + ty * 4 + i) * ldc + n] = v;
    }
}

// ---------------- scores / top-k / probs -> mask, inp ([u][4096][512], pad>=400 zero) ----------------
__global__ __launch_bounds__(256) void select_kernel(
    const float* __restrict__ q_l, const float* __restrict__ k_l,
    const void* __restrict__ key_b, const void* __restrict__ value_b,
    const float* __restrict__ v_l, const int* __restrict__ flagp,
    float* __restrict__ mask_out, u16* __restrict__ inp)
{
  const int b = blockIdx.x, tid = threadIdx.x;
  const int f32 = flagp[0];
  __shared__ float s_sc[16], s_pm[8], s_pm1[8];
  __shared__ float s_v[400], s_vb[400];
  const int task = tid >> 4, l16 = tid & 15, uu = task & 7;
  const float* qv = q_l + (size_t)b * 512 + uu * 64;
  float p = 0.f;
  if (task < 8) {
    const float* kv = k_l + (size_t)b * 64;
    for (int k = l16; k < 64; k += 16) p += qv[k] * kv[k];
  } else {
    for (int k = l16; k < 64; k += 16) p += qv[k] * ldin(key_b, k, f32);
  }
  p += __shfl_xor(p, 8, 16); p += __shfl_xor(p, 4, 16);
  p += __shfl_xor(p, 2, 16); p += __shfl_xor(p, 1, 16);
  if (l16 == 0) s_sc[task] = p * 0.125f;
  for (int i = tid; i < 400; i += 256) { s_v[i] = v_l[(size_t)b * 512 + i]; s_vb[i] = ldin(value_b, i, f32); }
  __syncthreads();
  if (tid < 8) {
    const float s0 = s_sc[tid];
    int rank = 0;
    for (int u2 = 0; u2 < 8; ++u2) {
      const float o = s_sc[u2];
      rank += (o > s0) || (o == s0 && u2 < tid);
    }
    const float m = (rank < 5) ? 1.f : 0.f;
    mask_out[(size_t)b * 8 + tid] = m;
    const float s1 = s_sc[8 + tid];
    const float mx = fmaxf(s0, s1);
    const float e0 = expf(s0 - mx), e1 = expf(s1 - mx);
    const float p0 = e0 / (e0 + e1);
    s_pm[tid] = m * p0; s_pm1[tid] = m * (1.f - p0);
  }
  __syncthreads();
#pragma unroll
  for (int u = 0; u < 8; ++u) {
    const float pm = s_pm[u], pm1 = s_pm1[u];
    for (int i = tid; i < 512; i += 256) {
      const float v = (i < 400) ? (pm * s_v[i] + pm1 * s_vb[i]) : 0.f;
      inp[((size_t)u * 4096 + b) * 512 + i] = f2bf(v);
    }
  }
}

// ---------------- shared 2-value block reduction (128 threads) ----------------
__device__ __forceinline__ void block_reduce_2(float& a, float& b) {
#pragma unroll
  for (int o = 32; o; o >>= 1) { a += __shfl_down(a, o, 64); b += __shfl_down(b, o, 64); }
  __shared__ float red[4];
  const int tid = threadIdx.x;
  if ((tid & 63) == 0) { red[(tid >> 6) * 2] = a; red[(tid >> 6) * 2 + 1] = b; }
  __syncthreads();
  a = red[0] + red[2]; b = red[1] + red[3];
}

// ---------------- GRU gates + per-unit LN -> out0, hb (grid = [MCG, 8]) ----------------
__global__ __launch_bounds__(128) void gates_kernel(
    const u16* __restrict__ gi, const u16* __restrict__ gh,
    const u16* __restrict__ hsb, const float* __restrict__ hmf,
    const u16* __restrict__ bhh, const u16* __restrict__ rng, const u16* __restrict__ rnb,
    const int* __restrict__ flagp, int bbase, void* __restrict__ out0, u16* __restrict__ hb)
{
  const int f = flagp[0];
  const int u = blockIdx.y, bl = blockIdx.x;
  const int b = bbase + bl;
  const int h0 = threadIdx.x * 4;
  const size_t rowg = ((size_t)u * gridDim.x + bl) * 1536;
  const size_t rowhs = ((size_t)b * 8 + u) * 512;
  const size_t rowhb = ((size_t)u * 4096 + b) * 512;
  float ir[4], iz[4], inn[4], hr[4], hz[4], hnn[4], hsv[4], br[4], bz[4], bn[4];
  ld4bf(gi + rowg + h0, ir);
  ld4bf(gi + rowg + 512 + h0, iz);
  ld4bf(gi + rowg + 1024 + h0, inn);
  ld4bf(gh + rowg + h0, hr);
  ld4bf(gh + rowg + 512 + h0, hz);
  ld4bf(gh + rowg + 1024 + h0, hnn);
  ld4bf(hsb + rowhs + h0, hsv);
  ld4bf(bhh + u * 1536 + h0, br);
  ld4bf(bhh + u * 1536 + 512 + h0, bz);
  ld4bf(bhh + u * 1536 + 1024 + h0, bn);
  const float hmask = hmf[b];
  float hn[4]; float sum = 0.f, sq = 0.f;
#pragma unroll
  for (int j = 0; j < 4; ++j) {
    const float hrf = hmask * hr[j] + br[j];
    const float hzf = hmask * hz[j] + bz[j];
    const float hnf = hmask * hnn[j] + bn[j];
    const float r = 1.f / (1.f + expf(-(ir[j] + hrf)));
    const float zz = 1.f / (1.f + expf(-(iz[j] + hzf)));
    const float n = tanhf(inn[j] + r * hnf);
    const float hmv = hsv[j] * hmask;
    const float h = (1.f - zz) * n + zz * hmv;
    hn[j] = h; sum += h; sq += h * h;
  }
  block_reduce_2(sum, sq);
  const float mean = sum * (1.f / 512.f);
  const float var = fmaxf(sq * (1.f / 512.f) - mean * mean, 0.f);
  const float rstd = rsqrtf(var + 1e-5f);
  float gg[4], bb[4];
  ld4bf(rng + u * 512 + h0, gg);
  ld4bf(rnb + u * 512 + h0, bb);
  float yv[4];
#pragma unroll
  for (int j = 0; j < 4; ++j) yv[j] = (hn[j] - mean) * rstd * gg[j] + bb[j];
  st4out(out0, (size_t)b * 4096 + u * 512 + h0, yv, f);
  ushort4 hv;
  hv.x = f2bf(hn[0]); hv.y = f2bf(hn[1]); hv.z = f2bf(hn[2]); hv.w = f2bf(hn[3]);
  *(ushort4*)(hb + rowhb + h0) = hv;
}

// ---------------- per-b 8x8 inter-unit attention -> ctx [u][MC][512] (pad>=400 zero) ----------------
__global__ __launch_bounds__(256) void attn_kernel(
    const u16* __restrict__ qvc, const float* __restrict__ maskp, int bbase,
    u16* __restrict__ ctx)
{
  const int bl = blockIdx.x, tid = threadIdx.x;
  const int b = bbase + bl;
  const size_t MC = gridDim.x;
  __shared__ float s_q[8][128], s_k[8][128];
  __shared__ float s_ap[4][8][8];
  __shared__ float s_v[8][400];
  for (int i = tid; i < 1024; i += 256) {
    const int u = i >> 7, c = i & 127;
    const size_t base = ((size_t)u * MC + bl) * 768;
    s_q[u][c] = b2f(qvc[base + c]);
    s_k[u][c] = b2f(qvc[base + 128 + c]);
  }
  for (int i = tid; i < 3200; i += 256) {
    const int u = i / 400, c = i - u * 400;
    s_v[u][c] = b2f(qvc[((size_t)u * MC + bl) * 768 + 256 + c]);
  }
  __syncthreads();
  const int n = tid >> 6, uu = (tid >> 3) & 7, vv = tid & 7;
  float a = 0.f;
#pragma unroll
  for (int k = 0; k < 32; ++k) a += s_q[uu][n * 32 + k] * s_k[vv][n * 32 + k];
  a *= 0.17677669529663687f;
  float mx = a;
  for (int o = 4; o; o >>= 1) mx = fmaxf(mx, __shfl_xor(mx, o, 8));
  const float e = expf(a - mx);
  float se = e;
  for (int o = 4; o; o >>= 1) se += __shfl_xor(se, o, 8);
  s_ap[n][uu][vv] = e / se * maskp[(size_t)b * 8 + uu];
  __syncthreads();
  for (int i = tid; i < 4096; i += 256) {
    const int u = i >> 9, c = i & 511;
    float v = 0.f;
    if (c < 400) {
      const int nn = c / 100;
      const float* ap = s_ap[nn][u];
#pragma unroll
      for (int v2 = 0; v2 < 8; ++v2) v += ap[v2] * s_v[v2][c];
    }
    ctx[((size_t)u * MC + bl) * 512 + c] = f2bf(v);
  }
}

// ---------------- final LN + masked blend -> out2 (grid = [MCC, 8]) ----------------
__global__ __launch_bounds__(128) void final_kernel(
    const u16* __restrict__ ctx2, const u16* __restrict__ hb, const u16* __restrict__ hsb,
    const float* __restrict__ maskp, const u16* __restrict__ lng, const u16* __restrict__ lnb,
    const int* __restrict__ flagp, int bbase, void* __restrict__ outp)
{
  const int f = flagp[0];
  const int u = blockIdx.y, bl = blockIdx.x;
  const int b = bbase + bl;
  const int h0 = threadIdx.x * 4;
  const size_t rowc = ((size_t)u * gridDim.x + bl) * 512;
  const size_t rowhs = ((size_t)b * 8 + u) * 512;
  const size_t rowhb = ((size_t)u * 4096 + b) * 512;
  float cv[4], hbv[4];
  ld4bf(ctx2 + rowc + h0, cv);
  ld4bf(hb + rowhb + h0, hbv);
  float v[4] = { cv[0] + hbv[0], cv[1] + hbv[1], cv[2] + hbv[2], cv[3] + hbv[3] };
  float sum = v[0] + v[1] + v[2] + v[3];
  float sq = v[0] * v[0] + v[1] * v[1] + v[2] * v[2] + v[3] * v[3];
  block_reduce_2(sum, sq);
  const float mean = sum * (1.f / 512.f);
  const float var = fmaxf(sq * (1.f / 512.f) - mean * mean, 0.f);
  const float rstd = rsqrtf(var + 1e-5f);
  float gg[4], bb2[4], hsv[4];
  ld4bf(lng + h0, gg); ld4bf(lnb + h0, bb2); ld4bf(hsb + rowhs + h0, hsv);
  const float msk = maskp[(size_t)b * 8 + u];
  float ov[4];
#pragma unroll
  for (int j = 0; j < 4; ++j)
    ov[j] = msk * ((v[j] - mean) * rstd * gg[j] + bb2[j]) + (1.f - msk) * hsv[j];
  st4out(outp, (size_t)16777216 + (size_t)(b * 8 + u) * 512 + h0, ov, f);
}

extern "C" void kernel_launch(void* const* d_in, const int* in_sizes, int n_in,
                              void* d_out, int out_size, void* d_ws, size_t ws_size,
                              hipStream_t stream) {
  const void* x       = d_in[0];
  const void* hs      = d_in[1];
  const void* h_masks = d_in[2];
  const void* key_w   = d_in[3];
  const void* key_b   = d_in[4];
  const void* value_w = d_in[5];
  const void* value_b = d_in[6];
  const void* query_w = d_in[7];
  const void* qc_w    = d_in[8];
  const void* kc_w    = d_in[9];
  const void* vc_w    = d_in[10];
  const void* out_w   = d_in[11];
  const void* ln_g    = d_in[12];
  const void* ln_b    = d_in[13];
  const void* W_ih    = d_in[14];
  const void* b_ih    = d_in[15];
  const void* W_hh    = d_in[16];
  const void* b_hh    = d_in[17];
  const void* rnn_g   = d_in[18];
  const void* rnn_b   = d_in[19];

  char* ws = (char*)d_ws;
  int*   FLAG = (int*)(ws + OFF_FLAG);
  u16*   WIH  = (u16*)(ws + OFF_WIH);
  u16*   WHH  = (u16*)(ws + OFF_WHH);
  u16*   QVW  = (u16*)(ws + OFF_QVW);
  u16*   OUTW = (u16*)(ws + OFF_OUTW);
  u16*   VALW = (u16*)(ws + OFF_VALW);
  u16*   VBP  = (u16*)(ws + OFF_VBP);
  u16*   BIH  = (u16*)(ws + OFF_BIH);
  u16*   BHH  = (u16*)(ws + OFF_BHH);
  u16*   RNG  = (u16*)(ws + OFF_RNG);
  u16*   RNB  = (u16*)(ws + OFF_RNB);
  u16*   LNG  = (u16*)(ws + OFF_LNG);
  u16*   LNB  = (u16*)(ws + OFF_LNB);
  float* HMF  = (float*)(ws + OFF_HMF);
  u16*   XB   = (u16*)(ws + OFF_XB);
  u16*   HSB  = (u16*)(ws + OFF_HSB);
  float* KL   = (float*)(ws + OFF_KL);
  float* VL   = (float*)(ws + OFF_VL);
  float* QL   = (float*)(ws + OFF_QL);
  float* MASK = (float*)(ws + OFF_MASK);
  u16*   HB   = (u16*)(ws + OFF_HB);
  u16*   INP  = (u16*)(ws + OFF_R);

  detect_kernel<<<1, 256, 0, stream>>>((const u16*)hs, FLAG);
  flatconv_kernel<<<15511, 256, 0, stream>>>(
      W_ih, W_hh, x, hs, value_b, b_ih, b_hh, rnn_g, rnn_b, ln_g, ln_b, h_masks, FLAG,
      WIH, WHH, XB, HSB, VBP, BIH, BHH, RNG, RNB, LNG, LNB, HMF);
  // weight transposes (dst[n][k] = src[k][n], zero-padded to Kp=512)
  transpose_kernel<<<dim3(8, 2, 8), 256, 0, stream>>>(qc_w,    FLAG, QVW,          512, 128, 512, 65536L,  393216L);
  transpose_kernel<<<dim3(8, 2, 8), 256, 0, stream>>>(kc_w,    FLAG, QVW + 65536,  512, 128, 512, 65536L,  393216L);
  transpose_kernel<<<dim3(8, 8, 8), 256, 0, stream>>>(vc_w,    FLAG, QVW + 131072, 512, 400, 512, 204800L, 393216L);
  transpose_kernel<<<dim3(8, 8, 8), 256, 0, stream>>>(out_w,   FLAG, OUTW,         400, 512, 512, 204800L, 262144L);
  transpose_kernel<<<dim3(8, 8, 1), 256, 0, stream>>>(value_w, FLAG, VALW,         512, 400, 512, 0L,      0L);
  // v_l = x @ value_w + value_b  (128^2 MFMA, f32 out)
  gemm_bt_kernel<0, 1><<<dim3(32, 4, 1), 256, 0, stream>>>(XB, VALW, VL, VBP, 512, 512, 0L, 0L, 0L, 0, 512);
  // score path: exact dtype (top-k stability)
  gemm_f32bf_kernel<<<dim3(64, 1, 1), 256, 0, stream>>>(x, key_w, KL, key_b, FLAG, 512, 512, 64, 64, 0L, 0L, 0L);
  gemm_f32bf_kernel<<<dim3(64, 1, 8), 256, 0, stream>>>(hs, query_w, QL, nullptr, FLAG, 512, 4096, 64, 512, 512L, 32768L, 64L);
  select_kernel<<<4096, 256, 0, stream>>>(QL, KL, key_b, value_b, VL, FLAG, MASK, INP);

  // ---- GRU: 8-phase GEMMs (T1+T2+fa-reuse+vec-epilogue), adaptive chunking ----
  const size_t base_g = OFF_R + 33554432UL;   // after INP [8][4096][512]
  int MCG = 4096;
  if (ws_size < base_g + 2UL * 8 * 4096 * 1536 * 2) MCG = 2048;
  if (ws_size < base_g + 2UL * 8 * 2048 * 1536 * 2) MCG = 1024;
  u16* GI = (u16*)(ws + base_g);
  u16* GH = GI + (size_t)8 * MCG * 1536;
  for (int c = 0; c < 4096 / MCG; ++c) {
    gemm8_kernel<1, 1><<<dim3(MCG / 256, 6, 8), 512, 0, stream>>>(
        INP + (size_t)c * MCG * 512, WIH, GI, BIH, 512, 2097152L, 786432L, (long)MCG * 1536, 1536, 1536);
    gemm8_kernel<1, 0><<<dim3(MCG / 256, 6, 8), 512, 0, stream>>>(
        HSB + (size_t)c * MCG * 4096, WHH, GH, nullptr, 4096, 512L, 786432L, (long)MCG * 1536, 0, 1536);
    gates_kernel<<<dim3(MCG, 8), 128, 0, stream>>>(GI, GH, HSB, HMF, BHH, RNG, RNB, FLAG, c * MCG, d_out, HB);
  }

  // ---- communication attention: 8-phase GEMMs, adaptive chunking ----
  int MCC = 4096;
  if (ws_size < OFF_R + (size_t)8 * 4096 * (768 + 512 + 512) * 2) MCC = 2048;
  u16* QVC  = (u16*)(ws + OFF_R);
  u16* CTX  = QVC + (size_t)8 * MCC * 768;
  u16* CTX2 = CTX + (size_t)8 * MCC * 512;
  for (int d2 = 0; d2 < 4096 / MCC; ++d2) {
    gemm8_kernel<1, 0><<<dim3(MCC / 256, 3, 8), 512, 0, stream>>>(
        HB + (size_t)d2 * MCC * 512, QVW, QVC, nullptr, 512, 2097152L, 393216L, (long)MCC * 768, 0, 768);
    attn_kernel<<<dim3(MCC), 256, 0, stream>>>(QVC, MASK, d2 * MCC, CTX);
    gemm8_kernel<1, 0><<<dim3(MCC / 256, 2, 8), 512, 0, stream>>>(
        CTX, OUTW, CTX2, nullptr, 512, (long)MCC * 512, 262144L, (long)MCC * 512, 0, 512);
    final_kernel<<<dim3(MCC, 8), 128, 0, stream>>>(CTX2, HB, HSB, MASK, LNG, LNB, FLAG, d2 * MCC, d_out);
  }
  (void)in_sizes; (void)n_in; (void)out_size; (void)ws_size;
}

// Round 11
// 517.019 us; speedup vs baseline: 1.0451x; 1.0451x over previous
//
#include <hip/hip_runtime.h>

typedef __attribute__((ext_vector_type(4))) float f32x4;
typedef __attribute__((ext_vector_type(8))) short bf16x8;
typedef unsigned short u16;

#define DEVINL static __device__ __forceinline__

DEVINL float b2f(u16 u) { union { unsigned int i; float f; } x; x.i = ((unsigned int)u) << 16; return x.f; }
DEVINL u16 f2bf(float f) {
  union { float f; unsigned int i; } x; x.f = f;
  unsigned int r = x.i + 0x7fffu + ((x.i >> 16) & 1u);
  return (u16)(r >> 16);
}
DEVINL float ldin(const void* p, long i, int f) {
  return f ? ((const float*)p)[i] : b2f(((const u16*)p)[i]);
}
DEVINL void ld4bf(const u16* p, float* o) {
  ushort4 v = *(const ushort4*)p;
  o[0] = b2f(v.x); o[1] = b2f(v.y); o[2] = b2f(v.z); o[3] = b2f(v.w);
}
DEVINL void st4out(void* out, size_t idx, const float* v, int f) {
  if (f) {
    float4 t; t.x = v[0]; t.y = v[1]; t.z = v[2]; t.w = v[3];
    *(float4*)((float*)out + idx) = t;
  } else {
    ushort4 t; t.x = f2bf(v[0]); t.y = f2bf(v[1]); t.z = f2bf(v[2]); t.w = f2bf(v[3]);
    *(ushort4*)((u16*)out + idx) = t;
  }
}
DEVINL void cv8(const void* s, long i, int f, u16* d) {
  if (f) {
    const float4 a = *(const float4*)((const float*)s + i);
    const float4 b = *(const float4*)((const float*)s + i + 4);
    ushort4 lo, hi;
    lo.x = f2bf(a.x); lo.y = f2bf(a.y); lo.z = f2bf(a.z); lo.w = f2bf(a.w);
    hi.x = f2bf(b.x); hi.y = f2bf(b.y); hi.z = f2bf(b.z); hi.w = f2bf(b.w);
    *(ushort4*)d = lo; *(ushort4*)(d + 4) = hi;
  } else {
    const ushort4 a = *(const ushort4*)((const u16*)s + i);
    const ushort4 b = *(const ushort4*)((const u16*)s + i + 4);
    *(ushort4*)d = a; *(ushort4*)(d + 4) = b;
  }
}

// ---------------- workspace layout (bytes); all GEMM K padded to 512 ----------------
static constexpr size_t OFF_FLAG = 0;
static constexpr size_t OFF_WIH  = 1024;        // bf16 [8][1536][512] (k>=400 zero)
static constexpr size_t OFF_WHH  = 12583936;    // bf16 [8][1536][512]
static constexpr size_t OFF_QVW  = 25166848;    // bf16 [8][768][512]
static constexpr size_t OFF_OUTW = 31458304;    // bf16 [8][512][512] (k>=400 zero)
static constexpr size_t OFF_VALW = 35652608;    // bf16 [512][512]
static constexpr size_t OFF_VBP  = 36176896;    // bf16 [512]
static constexpr size_t OFF_BIH  = 36177920;    // bf16 [8][1536]
static constexpr size_t OFF_BHH  = 36202496;    // bf16 [8][1536]
static constexpr size_t OFF_RNG  = 36227072;    // bf16 [8][512]
static constexpr size_t OFF_RNB  = 36235264;    // bf16 [8][512]
static constexpr size_t OFF_LNG  = 36243456;    // bf16 [512]
static constexpr size_t OFF_LNB  = 36244480;    // bf16 [512]
static constexpr size_t OFF_HMF  = 36245504;    // f32  [4096]
static constexpr size_t OFF_XB   = 36261888;    // bf16 [4096][512]
static constexpr size_t OFF_HSB  = 40456192;    // bf16 [4096][8][512] (straight hs copy)
static constexpr size_t OFF_KL   = 74010624;    // f32  [4096][64]
static constexpr size_t OFF_VL   = 75059200;    // f32  [4096][512]
static constexpr size_t OFF_QL   = 83447808;    // f32  [4096][512]
static constexpr size_t OFF_MASK = 91836416;    // f32  [4096][8]
static constexpr size_t OFF_HB   = 91967488;    // bf16 [8][4096][512]
static constexpr size_t OFF_R    = 125521920;   // reusable: INP[8][4096][512] + GI/GH | QVC/CTX/CTX2

// ---------------- dtype detect: even-u16 plausibility ----------------
__global__ __launch_bounds__(256) void detect_kernel(const u16* __restrict__ hs_u, int* __restrict__ flag) {
  __shared__ int cnt;
  if (threadIdx.x == 0) cnt = 0;
  __syncthreads();
  int ok = 0;
  for (int i = threadIdx.x; i < 1024; i += 256) {
    const float v = fabsf(b2f(hs_u[2 * i]));
    if (v > 9.094947e-13f && v < 1.0995116e12f) ok++;   // 2^-40 .. 2^40
  }
  atomicAdd(&cnt, ok);
  __syncthreads();
  if (threadIdx.x == 0) flag[0] = (cnt >= 921) ? 0 : 1;  // bf16(0) / fp32(1)
}

// ---------------- vectorized flat convert/pad (8 elems/thread) ----------------
__global__ __launch_bounds__(256) void flatconv_kernel(
    const void* __restrict__ W_ih, const void* __restrict__ W_hh, const void* __restrict__ x,
    const void* __restrict__ hs, const void* __restrict__ value_b, const void* __restrict__ b_ih,
    const void* __restrict__ b_hh, const void* __restrict__ rnn_g, const void* __restrict__ rnn_b,
    const void* __restrict__ ln_g, const void* __restrict__ ln_b, const void* __restrict__ h_masks,
    const int* __restrict__ flagp,
    u16* __restrict__ WIH, u16* __restrict__ WHH, u16* __restrict__ XB, u16* __restrict__ HSB,
    u16* __restrict__ VBP, u16* __restrict__ BIH, u16* __restrict__ BHH,
    u16* __restrict__ RNG, u16* __restrict__ RNB, u16* __restrict__ LNG, u16* __restrict__ LNB,
    float* __restrict__ HMF)
{
  const int f = flagp[0];
  long t = (long)blockIdx.x * 256 + threadIdx.x;
  if (t < 786432L) {                         // WIH [r=u*1536][512], pad k>=400
    const long r = t >> 6; const int k = (int)(t & 63) * 8;
    u16* d = WIH + r * 512 + k;
    if (k < 400) cv8(W_ih, r * 400 + k, f, d);
    else { ushort4 z{0,0,0,0}; *(ushort4*)d = z; *(ushort4*)(d + 4) = z; }
    return;
  }
  t -= 786432L;
  if (t < 786432L) { cv8(W_hh, t * 8, f, WHH + t * 8); return; }
  t -= 786432L;
  if (t < 262144L) { cv8(x, t * 8, f, XB + t * 8); return; }
  t -= 262144L;
  if (t < 2097152L) { cv8(hs, t * 8, f, HSB + t * 8); return; }
  t -= 2097152L;
  if (t < 512L) { VBP[t] = (t < 400) ? f2bf(ldin(value_b, t, f)) : (u16)0; return; }
  t -= 512L;
  if (t < 12288L) { BIH[t] = f2bf(ldin(b_ih, t, f)); return; }
  t -= 12288L;
  if (t < 12288L) { BHH[t] = f2bf(ldin(b_hh, t, f)); return; }
  t -= 12288L;
  if (t < 4096L) { RNG[t] = f2bf(ldin(rnn_g, t, f)); return; }
  t -= 4096L;
  if (t < 4096L) { RNB[t] = f2bf(ldin(rnn_b, t, f)); return; }
  t -= 4096L;
  if (t < 512L) { LNG[t] = f2bf(ldin(ln_g, t, f)); return; }
  t -= 512L;
  if (t < 512L) { LNB[t] = f2bf(ldin(ln_b, t, f)); return; }
  t -= 512L;
  if (t < 4096L) { HMF[t] = ldin(h_masks, t, f); return; }
}

// ---------------- LDS-tiled transpose: dst[z][n][k](bf16,[*][Kp]) = src[z][k][n], zero-pad ----------------
__global__ __launch_bounds__(256) void transpose_kernel(
    const void* __restrict__ src, const int* __restrict__ flagp, u16* __restrict__ dst,
    int K, int N, int Kp, long srcZ, long dstZ)
{
  const int f = flagp[0];
  __shared__ float t[64][65];
  const int k0 = blockIdx.x * 64, n0 = blockIdx.y * 64, z = blockIdx.z;
  const int tid = threadIdx.x;
  const int lk = tid >> 4;
  const int ln4 = (tid & 15) * 4;
#pragma unroll
  for (int p = 0; p < 4; ++p) {
    const int k = k0 + lk + p * 16;
    float v[4] = {0.f, 0.f, 0.f, 0.f};
    if (k < K) {
      const long base = srcZ * z + (long)k * N + n0 + ln4;
#pragma unroll
      for (int j = 0; j < 4; ++j)
        if (n0 + ln4 + j < N) v[j] = ldin(src, base + j, f);
    }
    t[lk + p * 16][ln4 + 0] = v[0]; t[lk + p * 16][ln4 + 1] = v[1];
    t[lk + p * 16][ln4 + 2] = v[2]; t[lk + p * 16][ln4 + 3] = v[3];
  }
  __syncthreads();
#pragma unroll
  for (int p = 0; p < 4; ++p) {
    const int n = n0 + lk + p * 16;
    ushort4 o;
    o.x = f2bf(t[ln4 + 0][lk + p * 16]);
    o.y = f2bf(t[ln4 + 1][lk + p * 16]);
    o.z = f2bf(t[ln4 + 2][lk + p * 16]);
    o.w = f2bf(t[ln4 + 3][lk + p * 16]);
    *(ushort4*)&dst[dstZ * z + (long)n * Kp + k0 + ln4] = o;
  }
}

// ---------------- 8-phase 256x256 MFMA NT GEMM, K=512 (T1+T2+T3+T4+T5, fa-reuse) ----------------
// Round-9 configuration (best measured). Epilogue bias hoisted per-nf (FP order unchanged).
template<int OUT_BF16, int HAS_BIAS>
__global__ __launch_bounds__(512, 2) void gemm8_kernel(
    const u16* __restrict__ A, const u16* __restrict__ W, void* __restrict__ Cp,
    const u16* __restrict__ bias, int ldaE, long Az, long Wz, long Cz, int Bz, int ldc)
{
  __shared__ u16 lds[65536];   // 128 KiB
  const int tid = threadIdx.x;
  const int w = tid >> 6, l = tid & 63;
  const int wr = w >> 2, wc = w & 3;
  const int lr = l & 15, kg = l >> 4;
  const int l3 = l >> 3;
  const int l7ks = ((l & 7) ^ l3) * 8;       // T2 inverse-swizzled source col (elems)
  const int lswz = (lr & 7) << 3;            // T2 read swizzle (elems)

  // T1: bijective XCD swizzle (requires nwg % 8 == 0), by-fastest for A-panel L2 reuse
  int bx, by, bz;
  {
    const int gx = gridDim.x, gy = gridDim.y;
    const int nwg = gx * gy * (int)gridDim.z;
    int flat = (int)blockIdx.x + gx * ((int)blockIdx.y + gy * (int)blockIdx.z);
    flat = (flat & 7) * (nwg >> 3) + (flat >> 3);
    by = flat % gy; const int tmp = flat / gy;
    bx = tmp % gx; bz = tmp / gx;
  }
  const int m0 = bx * 256, n0 = by * 256, z = bz;
  const u16* Au = A + (size_t)z * Az;
  const u16* Wu = W + (size_t)z * Wz;

  f32x4 acc[8][4];
#pragma unroll
  for (int i = 0; i < 8; ++i)
#pragma unroll
    for (int j = 0; j < 4; ++j) acc[i][j] = (f32x4){0.f, 0.f, 0.f, 0.f};

  bf16x8 fa[2][4], fb[2][2];

#define GL8(srcp, dstoff) __builtin_amdgcn_global_load_lds( \
    (const __attribute__((address_space(1))) void*)(srcp), \
    (__attribute__((address_space(3))) void*)((char*)lds + 2 * (dstoff)), 16, 0, 0)

#define STAGE_A8(t, mh, slot) do { \
  _Pragma("unroll") for (int c_ = 0; c_ < 2; ++c_) { \
    const int row0_ = (mh) * 64 + w * 8 + c_ * 128; \
    GL8(Au + (size_t)(m0 + row0_ + l3) * ldaE + (t) * 64 + l7ks, (slot) * 16384 + row0_ * 64); \
  } } while (0)

#define STAGE_B8(t, nh, slot) do { \
  _Pragma("unroll") for (int c_ = 0; c_ < 2; ++c_) { \
    const int rq0_ = w * 8 + c_ * 64; \
    const int row0_ = ((rq0_ >> 5) << 6) + (nh) * 32 + (rq0_ & 31); \
    GL8(Wu + (size_t)(n0 + row0_ + l3) * 512 + (t) * 64 + l7ks, 32768 + (slot) * 16384 + row0_ * 64); \
  } } while (0)

#define VMW4 asm volatile("s_waitcnt vmcnt(4)" ::: "memory")

#define LOAD_FA(sl, mh) do { \
  _Pragma("unroll") for (int kk = 0; kk < 2; ++kk) \
    _Pragma("unroll") for (int mq = 0; mq < 4; ++mq) \
      fa[kk][mq] = *(const bf16x8*)&lds[(sl) * 16384 + (wr * 128 + (mh) * 64 + mq * 16 + lr) * 64 + ((kk * 32 + kg * 8) ^ lswz)]; \
} while (0)

#define LOAD_FB(sl, nh) do { \
  _Pragma("unroll") for (int kk = 0; kk < 2; ++kk) \
    _Pragma("unroll") for (int nq = 0; nq < 2; ++nq) \
      fb[kk][nq] = *(const bf16x8*)&lds[32768 + (sl) * 16384 + (wc * 64 + (nh) * 32 + nq * 16 + lr) * 64 + ((kk * 32 + kg * 8) ^ lswz)]; \
} while (0)

#define PHASE_MM(mh, nh, STG, VMW) do { \
  STG; \
  asm volatile("" ::: "memory"); \
  __builtin_amdgcn_s_barrier(); \
  __builtin_amdgcn_s_setprio(1); \
  _Pragma("unroll") for (int kk = 0; kk < 2; ++kk) \
    _Pragma("unroll") for (int mq = 0; mq < 4; ++mq) \
      _Pragma("unroll") for (int nq = 0; nq < 2; ++nq) \
        acc[(mh) * 4 + mq][(nh) * 2 + nq] = __builtin_amdgcn_mfma_f32_16x16x32_bf16( \
            fa[kk][mq], fb[kk][nq], acc[(mh) * 4 + mq][(nh) * 2 + nq], 0, 0, 0); \
  __builtin_amdgcn_s_setprio(0); \
  VMW; \
  asm volatile("" ::: "memory"); \
  __builtin_amdgcn_s_barrier(); \
} while (0)

  // prologue: slot0 full (tile 0) + slot1 A0,B0 (tile 1); keep slot1's 4 in flight
  STAGE_A8(0, 0, 0); STAGE_A8(0, 1, 0); STAGE_B8(0, 0, 0); STAGE_B8(0, 1, 0);
  STAGE_A8(1, 0, 1); STAGE_B8(1, 0, 1);
  asm volatile("s_waitcnt vmcnt(4)" ::: "memory");
  __builtin_amdgcn_s_barrier();

  for (int i = 0; i < 4; ++i) {
    const int tB = 2 * i + 1, tC = (2 * i + 2) & 7, tD = (2 * i + 3) & 7;
    LOAD_FA(0, 0); LOAD_FB(0, 0);
    PHASE_MM(0, 0, STAGE_A8(tB, 1, 1), );
    LOAD_FB(0, 1);
    PHASE_MM(0, 1, STAGE_B8(tB, 1, 1), );
    LOAD_FA(0, 1); LOAD_FB(0, 0);
    PHASE_MM(1, 0, STAGE_A8(tC, 0, 0), );
    LOAD_FB(0, 1);
    PHASE_MM(1, 1, STAGE_B8(tC, 0, 0), VMW4);
    LOAD_FA(1, 0); LOAD_FB(1, 0);
    PHASE_MM(0, 0, STAGE_A8(tC, 1, 0), );
    LOAD_FB(1, 1);
    PHASE_MM(0, 1, STAGE_B8(tC, 1, 0), );
    LOAD_FA(1, 1); LOAD_FB(1, 0);
    PHASE_MM(1, 0, STAGE_A8(tD, 0, 1), );
    LOAD_FB(1, 1);
    PHASE_MM(1, 1, STAGE_B8(tD, 0, 1), VMW4);
  }
  asm volatile("s_waitcnt vmcnt(0)" ::: "memory");

  float bvs[4];
#pragma unroll
  for (int nf = 0; nf < 4; ++nf)
    bvs[nf] = HAS_BIAS ? b2f(bias[(size_t)z * Bz + n0 + wc * 64 + nf * 16 + lr]) : 0.f;
  float* Cf = (float*)Cp;
  u16* Cb = (u16*)Cp;
#pragma unroll
  for (int mf = 0; mf < 8; ++mf) {
#pragma unroll
    for (int nf = 0; nf < 4; ++nf) {
      const int gc = n0 + wc * 64 + nf * 16 + lr;
#pragma unroll
      for (int t = 0; t < 4; ++t) {
        const int gr = m0 + wr * 128 + mf * 16 + kg * 4 + t;   // C/D: col=lane&15, row=(lane>>4)*4+reg
        const float v = acc[mf][nf][t] + bvs[nf];
        const size_t idx = (size_t)z * Cz + (size_t)gr * ldc + gc;
        if (OUT_BF16) Cb[idx] = f2bf(v); else Cf[idx] = v;
      }
    }
  }
#undef GL8
#undef STAGE_A8
#undef STAGE_B8
#undef VMW4
#undef LOAD_FA
#undef LOAD_FB
#undef PHASE_MM
}

// ---------------- 128x128 MFMA NT GEMM (verified; kept for VL) ----------------
template<int OUT_BF16, int HAS_BIAS>
__global__ __launch_bounds__(256) void gemm_bt_kernel(
    const u16* __restrict__ A, const u16* __restrict__ W, void* __restrict__ Cp,
    const u16* __restrict__ bias, int KP, int ldaE, long Az, long Wz, long Cz, int Bz, int ldc)
{
  __shared__ u16 lA[128 * 64];
  __shared__ u16 lB[128 * 64];
  const int tid = threadIdx.x;
  const int m0 = blockIdx.x * 128, n0 = blockIdx.y * 128, z = blockIdx.z;
  const u16* Au = A + (size_t)z * Az;
  const u16* Wu = W + (size_t)z * Wz;
  const int l = tid & 63, w = tid >> 6;
  const int WM = (w >> 1) * 64, WN = (w & 1) * 64;
  const int lr = l & 15, kg = l >> 4;
  f32x4 acc[4][4];
#pragma unroll
  for (int i = 0; i < 4; ++i)
#pragma unroll
    for (int j = 0; j < 4; ++j) acc[i][j] = (f32x4){0.f, 0.f, 0.f, 0.f};
  const int rowA = tid >> 3;
  const int cb = (tid & 7) * 16;
  const size_t rowBytesA = (size_t)ldaE * 2;
  const size_t rowBytesW = (size_t)KP * 2;
  for (int k0 = 0; k0 < KP; k0 += 64) {
    __syncthreads();
    const char* gA = (const char*)Au + (size_t)(m0 + rowA) * rowBytesA + (size_t)k0 * 2 + cb;
    const char* gB = (const char*)Wu + (size_t)(n0 + rowA) * rowBytesW + (size_t)k0 * 2 + cb;
    char* sA = (char*)lA + (w << 10);
    char* sB = (char*)lB + (w << 10);
#pragma unroll
    for (int c = 0; c < 4; ++c) {
      __builtin_amdgcn_global_load_lds(
          (const __attribute__((address_space(1))) void*)(gA + (size_t)c * 32 * rowBytesA),
          (__attribute__((address_space(3))) void*)(sA + c * 4096), 16, 0, 0);
      __builtin_amdgcn_global_load_lds(
          (const __attribute__((address_space(1))) void*)(gB + (size_t)c * 32 * rowBytesW),
          (__attribute__((address_space(3))) void*)(sB + c * 4096), 16, 0, 0);
    }
    __syncthreads();
#pragma unroll
    for (int kk = 0; kk < 64; kk += 32) {
      bf16x8 af[4], bw[4];
#pragma unroll
      for (int i = 0; i < 4; ++i)
        af[i] = *(const bf16x8*)&lA[(WM + i * 16 + lr) * 64 + kk + kg * 8];
#pragma unroll
      for (int j = 0; j < 4; ++j)
        bw[j] = *(const bf16x8*)&lB[(WN + j * 16 + lr) * 64 + kk + kg * 8];
#pragma unroll
      for (int i = 0; i < 4; ++i)
#pragma unroll
        for (int j = 0; j < 4; ++j)
          acc[i][j] = __builtin_amdgcn_mfma_f32_16x16x32_bf16(af[i], bw[j], acc[i][j], 0, 0, 0);
    }
  }
  float* Cf = (float*)Cp;
  u16* Cb = (u16*)Cp;
#pragma unroll
  for (int i = 0; i < 4; ++i) {
#pragma unroll
    for (int j = 0; j < 4; ++j) {
      const int gc = n0 + WN + j * 16 + lr;
      float bv = 0.f;
      if (HAS_BIAS) bv = b2f(bias[(size_t)z * Bz + gc]);
#pragma unroll
      for (int t = 0; t < 4; ++t) {
        const int gr = m0 + WM + i * 16 + kg * 4 + t;
        const float v = acc[i][j][t] + bv;
        const size_t idx = (size_t)z * Cz + (size_t)gr * ldc + gc;
        if (OUT_BF16) Cb[idx] = f2bf(v); else Cf[idx] = v;
      }
    }
  }
}

// ---------------- exact-dtype fp32 GEMM for the score path ----------------
__global__ __launch_bounds__(256) void gemm_f32bf_kernel(
    const void* __restrict__ A, const void* __restrict__ W, float* __restrict__ C,
    const void* __restrict__ bias, const int* __restrict__ flagp,
    int K, int lda, int ldw, int ldc, long Az, long Wz, long Cz)
{
  const int f32 = flagp[0];
  __shared__ float sA[16][65];
  __shared__ float sW[16][64];
  const int tid = threadIdx.x;
  const int m0 = blockIdx.x * 64, n0 = blockIdx.y * 64, z = blockIdx.z;
  const int tx = tid & 15, ty = tid >> 4;
  const int ar = tid >> 2, ak = (tid & 3) * 4;
  const int wk = tid >> 4, wc = (tid & 15) * 4;
  const size_t abase = (size_t)z * Az, wbase = (size_t)z * Wz;
  float acc[4][4] = {};
  for (int k0 = 0; k0 < K; k0 += 16) {
    __syncthreads();
    float a0, a1, a2, a3, w0, w1, w2, w3;
    const size_t ai = abase + (size_t)(m0 + ar) * lda + k0 + ak;
    const size_t wi = wbase + (size_t)(k0 + wk) * ldw + n0 + wc;
    if (f32) {
      const float4 av = *(const float4*)((const float*)A + ai);
      const float4 wv = *(const float4*)((const float*)W + wi);
      a0 = av.x; a1 = av.y; a2 = av.z; a3 = av.w;
      w0 = wv.x; w1 = wv.y; w2 = wv.z; w3 = wv.w;
    } else {
      const ushort4 av = *(const ushort4*)((const u16*)A + ai);
      const ushort4 wv = *(const ushort4*)((const u16*)W + wi);
      a0 = b2f(av.x); a1 = b2f(av.y); a2 = b2f(av.z); a3 = b2f(av.w);
      w0 = b2f(wv.x); w1 = b2f(wv.y); w2 = b2f(wv.z); w3 = b2f(wv.w);
    }
    sA[ak + 0][ar] = a0; sA[ak + 1][ar] = a1; sA[ak + 2][ar] = a2; sA[ak + 3][ar] = a3;
    sW[wk][wc] = w0; sW[wk][wc + 1] = w1; sW[wk][wc + 2] = w2; sW[wk][wc + 3] = w3;
    __syncthreads();
#pragma unroll
    for (int kk = 0; kk < 16; ++kk) {
      const float a0c = sA[kk][ty * 4 + 0], a1c = sA[kk][ty * 4 + 1];
      const float a2c = sA[kk][ty * 4 + 2], a3c = sA[kk][ty * 4 + 3];
      const float4 bv = *(const float4*)&sW[kk][tx * 4];
      acc[0][0] += a0c * bv.x; acc[0][1] += a0c * bv.y; acc[0][2] += a0c * bv.z; acc[0][3] += a0c * bv.w;
      acc[1][0] += a1c * bv.x; acc[1][1] += a1c * bv.y; acc[1][2] += a1c * bv.z; acc[1][3] += a1c * bv.w;
      acc[2][0] += a2c * bv.x; acc[2][1] += a2c * bv.y; acc[2][2] += a2c * bv.z; acc[2][3] += a2c * bv.w;
      acc[3][0] += a3c * bv.x; acc[3][1] += a3c * bv.y; acc[3][2] += a3c * bv.z; acc[3][3] += a3c * bv.w;
    }
  }
#pragma unroll
  for (int i = 0; i < 4; ++i)
#pragma unroll
    for (int j = 0; j < 4; ++j) {
      const int n = n0 + tx * 4 + j;
      float v = acc[i][j];
      if (bias) v += ldin(bias, n, f32);
      C[(size_t)z * Cz + (size_t)(m0 + ty * 4 + i) * ldc + n] = v;
    }
}

// ---------------- scores / top-k / probs -> mask, inp ([u][4096][512], pad>=400 zero) ----------------
__global__ __launch_bounds__(256) void select_kernel(
    const float* __restrict__ q_l, const float* __restrict__ k_l,
    const void* __restrict__ key_b, const void* __restrict__ value_b,
    const float* __restrict__ v_l, const int* __restrict__ flagp,
    float* __restrict__ mask_out, u16* __restrict__ inp)
{
  const int b = blockIdx.x, tid = threadIdx.x;
  const int f32 = flagp[0];
  __shared__ float s_sc[16], s_pm[8], s_pm1[8];
  __shared__ float s_v[400], s_vb[400];
  const int task = tid >> 4, l16 = tid & 15, uu = task & 7;
  const float* qv = q_l + (size_t)b * 512 + uu * 64;
  float p = 0.f;
  if (task < 8) {
    const float* kv = k_l + (size_t)b * 64;
    for (int k = l16; k < 64; k += 16) p += qv[k] * kv[k];
  } else {
    for (int k = l16; k < 64; k += 16) p += qv[k] * ldin(key_b, k, f32);
  }
  p += __shfl_xor(p, 8, 16); p += __shfl_xor(p, 4, 16);
  p += __shfl_xor(p, 2, 16); p += __shfl_xor(p, 1, 16);
  if (l16 == 0) s_sc[task] = p * 0.125f;
  for (int i = tid; i < 400; i += 256) { s_v[i] = v_l[(size_t)b * 512 + i]; s_vb[i] = ldin(value_b, i, f32); }
  __syncthreads();
  if (tid < 8) {
    const float s0 = s_sc[tid];
    int rank = 0;
    for (int u2 = 0; u2 < 8; ++u2) {
      const float o = s_sc[u2];
      rank += (o > s0) || (o == s0 && u2 < tid);
    }
    const float m = (rank < 5) ? 1.f : 0.f;
    mask_out[(size_t)b * 8 + tid] = m;
    const float s1 = s_sc[8 + tid];
    const float mx = fmaxf(s0, s1);
    const float e0 = expf(s0 - mx), e1 = expf(s1 - mx);
    const float p0 = e0 / (e0 + e1);
    s_pm[tid] = m * p0; s_pm1[tid] = m * (1.f - p0);
  }
  __syncthreads();
#pragma unroll
  for (int u = 0; u < 8; ++u) {
    const float pm = s_pm[u], pm1 = s_pm1[u];
    for (int i = tid; i < 512; i += 256) {
      const float v = (i < 400) ? (pm * s_v[i] + pm1 * s_vb[i]) : 0.f;
      inp[((size_t)u * 4096 + b) * 512 + i] = f2bf(v);
    }
  }
}

// ---------------- shared 2-value block reduction (128 threads) ----------------
__device__ __forceinline__ void block_reduce_2(float& a, float& b) {
#pragma unroll
  for (int o = 32; o; o >>= 1) { a += __shfl_down(a, o, 64); b += __shfl_down(b, o, 64); }
  __shared__ float red[4];
  const int tid = threadIdx.x;
  if ((tid & 63) == 0) { red[(tid >> 6) * 2] = a; red[(tid >> 6) * 2 + 1] = b; }
  __syncthreads();
  a = red[0] + red[2]; b = red[1] + red[3];
}

// ---------------- GRU gates + per-unit LN -> out0, hb (grid = [MCG, 8]) ----------------
__global__ __launch_bounds__(128) void gates_kernel(
    const u16* __restrict__ gi, const u16* __restrict__ gh,
    const u16* __restrict__ hsb, const float* __restrict__ hmf,
    const u16* __restrict__ bhh, const u16* __restrict__ rng, const u16* __restrict__ rnb,
    const int* __restrict__ flagp, int bbase, void* __restrict__ out0, u16* __restrict__ hb)
{
  const int f = flagp[0];
  const int u = blockIdx.y, bl = blockIdx.x;
  const int b = bbase + bl;
  const int h0 = threadIdx.x * 4;
  const size_t rowg = ((size_t)u * gridDim.x + bl) * 1536;
  const size_t rowhs = ((size_t)b * 8 + u) * 512;
  const size_t rowhb = ((size_t)u * 4096 + b) * 512;
  float ir[4], iz[4], inn[4], hr[4], hz[4], hnn[4], hsv[4], br[4], bz[4], bn[4];
  ld4bf(gi + rowg + h0, ir);
  ld4bf(gi + rowg + 512 + h0, iz);
  ld4bf(gi + rowg + 1024 + h0, inn);
  ld4bf(gh + rowg + h0, hr);
  ld4bf(gh + rowg + 512 + h0, hz);
  ld4bf(gh + rowg + 1024 + h0, hnn);
  ld4bf(hsb + rowhs + h0, hsv);
  ld4bf(bhh + u * 1536 + h0, br);
  ld4bf(bhh + u * 1536 + 512 + h0, bz);
  ld4bf(bhh + u * 1536 + 1024 + h0, bn);
  const float hmask = hmf[b];
  float hn[4]; float sum = 0.f, sq = 0.f;
#pragma unroll
  for (int j = 0; j < 4; ++j) {
    const float hrf = hmask * hr[j] + br[j];
    const float hzf = hmask * hz[j] + bz[j];
    const float hnf = hmask * hnn[j] + bn[j];
    const float r = 1.f / (1.f + expf(-(ir[j] + hrf)));
    const float zz = 1.f / (1.f + expf(-(iz[j] + hzf)));
    const float n = tanhf(inn[j] + r * hnf);
    const float hmv = hsv[j] * hmask;
    const float h = (1.f - zz) * n + zz * hmv;
    hn[j] = h; sum += h; sq += h * h;
  }
  block_reduce_2(sum, sq);
  const float mean = sum * (1.f / 512.f);
  const float var = fmaxf(sq * (1.f / 512.f) - mean * mean, 0.f);
  const float rstd = rsqrtf(var + 1e-5f);
  float gg[4], bb[4];
  ld4bf(rng + u * 512 + h0, gg);
  ld4bf(rnb + u * 512 + h0, bb);
  float yv[4];
#pragma unroll
  for (int j = 0; j < 4; ++j) yv[j] = (hn[j] - mean) * rstd * gg[j] + bb[j];
  st4out(out0, (size_t)b * 4096 + u * 512 + h0, yv, f);
  ushort4 hv;
  hv.x = f2bf(hn[0]); hv.y = f2bf(hn[1]); hv.z = f2bf(hn[2]); hv.w = f2bf(hn[3]);
  *(ushort4*)(hb + rowhb + h0) = hv;
}

// ---------------- per-b 8x8 inter-unit attention -> ctx [u][MC][512] (pad>=400 zero) ----------------
__global__ __launch_bounds__(256) void attn_kernel(
    const u16* __restrict__ qvc, const float* __restrict__ maskp, int bbase,
    u16* __restrict__ ctx)
{
  const int bl = blockIdx.x, tid = threadIdx.x;
  const int b = bbase + bl;
  const size_t MC = gridDim.x;
  __shared__ float s_q[8][128], s_k[8][128];
  __shared__ float s_ap[4][8][8];
  __shared__ float s_v[8][400];
  for (int i = tid; i < 1024; i += 256) {
    const int u = i >> 7, c = i & 127;
    const size_t base = ((size_t)u * MC + bl) * 768;
    s_q[u][c] = b2f(qvc[base + c]);
    s_k[u][c] = b2f(qvc[base + 128 + c]);
  }
  for (int i = tid; i < 3200; i += 256) {
    const int u = i / 400, c = i - u * 400;
    s_v[u][c] = b2f(qvc[((size_t)u * MC + bl) * 768 + 256 + c]);
  }
  __syncthreads();
  const int n = tid >> 6, uu = (tid >> 3) & 7, vv = tid & 7;
  float a = 0.f;
#pragma unroll
  for (int k = 0; k < 32; ++k) a += s_q[uu][n * 32 + k] * s_k[vv][n * 32 + k];
  a *= 0.17677669529663687f;
  float mx = a;
  for (int o = 4; o; o >>= 1) mx = fmaxf(mx, __shfl_xor(mx, o, 8));
  const float e = expf(a - mx);
  float se = e;
  for (int o = 4; o; o >>= 1) se += __shfl_xor(se, o, 8);
  s_ap[n][uu][vv] = e / se * maskp[(size_t)b * 8 + uu];
  __syncthreads();
  for (int i = tid; i < 4096; i += 256) {
    const int u = i >> 9, c = i & 511;
    float v = 0.f;
    if (c < 400) {
      const int nn = c / 100;
      const float* ap = s_ap[nn][u];
#pragma unroll
      for (int v2 = 0; v2 < 8; ++v2) v += ap[v2] * s_v[v2][c];
    }
    ctx[((size_t)u * MC + bl) * 512 + c] = f2bf(v);
  }
}

// ---------------- final LN + masked blend -> out2 (grid = [MCC, 8]) ----------------
__global__ __launch_bounds__(128) void final_kernel(
    const u16* __restrict__ ctx2, const u16* __restrict__ hb, const u16* __restrict__ hsb,
    const float* __restrict__ maskp, const u16* __restrict__ lng, const u16* __restrict__ lnb,
    const int* __restrict__ flagp, int bbase, void* __restrict__ outp)
{
  const int f = flagp[0];
  const int u = blockIdx.y, bl = blockIdx.x;
  const int b = bbase + bl;
  const int h0 = threadIdx.x * 4;
  const size_t rowc = ((size_t)u * gridDim.x + bl) * 512;
  const size_t rowhs = ((size_t)b * 8 + u) * 512;
  const size_t rowhb = ((size_t)u * 4096 + b) * 512;
  float cv[4], hbv[4];
  ld4bf(ctx2 + rowc + h0, cv);
  ld4bf(hb + rowhb + h0, hbv);
  float v[4] = { cv[0] + hbv[0], cv[1] + hbv[1], cv[2] + hbv[2], cv[3] + hbv[3] };
  float sum = v[0] + v[1] + v[2] + v[3];
  float sq = v[0] * v[0] + v[1] * v[1] + v[2] * v[2] + v[3] * v[3];
  block_reduce_2(sum, sq);
  const float mean = sum * (1.f / 512.f);
  const float var = fmaxf(sq * (1.f / 512.f) - mean * mean, 0.f);
  const float rstd = rsqrtf(var + 1e-5f);
  float gg[4], bb2[4], hsv[4];
  ld4bf(lng + h0, gg); ld4bf(lnb + h0, bb2); ld4bf(hsb + rowhs + h0, hsv);
  const float msk = maskp[(size_t)b * 8 + u];
  float ov[4];
#pragma unroll
  for (int j = 0; j < 4; ++j)
    ov[j] = msk * ((v[j] - mean) * rstd * gg[j] + bb2[j]) + (1.f - msk) * hsv[j];
  st4out(outp, (size_t)16777216 + (size_t)(b * 8 + u) * 512 + h0, ov, f);
}

extern "C" void kernel_launch(void* const* d_in, const int* in_sizes, int n_in,
                              void* d_out, int out_size, void* d_ws, size_t ws_size,
                              hipStream_t stream) {
  const void* x       = d_in[0];
  const void* hs      = d_in[1];
  const void* h_masks = d_in[2];
  const void* key_w   = d_in[3];
  const void* key_b   = d_in[4];
  const void* value_w = d_in[5];
  const void* value_b = d_in[6];
  const void* query_w = d_in[7];
  const void* qc_w    = d_in[8];
  const void* kc_w    = d_in[9];
  const void* vc_w    = d_in[10];
  const void* out_w   = d_in[11];
  const void* ln_g    = d_in[12];
  const void* ln_b    = d_in[13];
  const void* W_ih    = d_in[14];
  const void* b_ih    = d_in[15];
  const void* W_hh    = d_in[16];
  const void* b_hh    = d_in[17];
  const void* rnn_g   = d_in[18];
  const void* rnn_b   = d_in[19];

  char* ws = (char*)d_ws;
  int*   FLAG = (int*)(ws + OFF_FLAG);
  u16*   WIH  = (u16*)(ws + OFF_WIH);
  u16*   WHH  = (u16*)(ws + OFF_WHH);
  u16*   QVW  = (u16*)(ws + OFF_QVW);
  u16*   OUTW = (u16*)(ws + OFF_OUTW);
  u16*   VALW = (u16*)(ws + OFF_VALW);
  u16*   VBP  = (u16*)(ws + OFF_VBP);
  u16*   BIH  = (u16*)(ws + OFF_BIH);
  u16*   BHH  = (u16*)(ws + OFF_BHH);
  u16*   RNG  = (u16*)(ws + OFF_RNG);
  u16*   RNB  = (u16*)(ws + OFF_RNB);
  u16*   LNG  = (u16*)(ws + OFF_LNG);
  u16*   LNB  = (u16*)(ws + OFF_LNB);
  float* HMF  = (float*)(ws + OFF_HMF);
  u16*   XB   = (u16*)(ws + OFF_XB);
  u16*   HSB  = (u16*)(ws + OFF_HSB);
  float* KL   = (float*)(ws + OFF_KL);
  float* VL   = (float*)(ws + OFF_VL);
  float* QL   = (float*)(ws + OFF_QL);
  float* MASK = (float*)(ws + OFF_MASK);
  u16*   HB   = (u16*)(ws + OFF_HB);
  u16*   INP  = (u16*)(ws + OFF_R);

  detect_kernel<<<1, 256, 0, stream>>>((const u16*)hs, FLAG);
  flatconv_kernel<<<15511, 256, 0, stream>>>(
      W_ih, W_hh, x, hs, value_b, b_ih, b_hh, rnn_g, rnn_b, ln_g, ln_b, h_masks, FLAG,
      WIH, WHH, XB, HSB, VBP, BIH, BHH, RNG, RNB, LNG, LNB, HMF);
  // weight transposes (dst[n][k] = src[k][n], zero-padded to Kp=512)
  transpose_kernel<<<dim3(8, 2, 8), 256, 0, stream>>>(qc_w,    FLAG, QVW,          512, 128, 512, 65536L,  393216L);
  transpose_kernel<<<dim3(8, 2, 8), 256, 0, stream>>>(kc_w,    FLAG, QVW + 65536,  512, 128, 512, 65536L,  393216L);
  transpose_kernel<<<dim3(8, 8, 8), 256, 0, stream>>>(vc_w,    FLAG, QVW + 131072, 512, 400, 512, 204800L, 393216L);
  transpose_kernel<<<dim3(8, 8, 8), 256, 0, stream>>>(out_w,   FLAG, OUTW,         400, 512, 512, 204800L, 262144L);
  transpose_kernel<<<dim3(8, 8, 1), 256, 0, stream>>>(value_w, FLAG, VALW,         512, 400, 512, 0L,      0L);
  // v_l = x @ value_w + value_b  (128^2 MFMA, f32 out)
  gemm_bt_kernel<0, 1><<<dim3(32, 4, 1), 256, 0, stream>>>(XB, VALW, VL, VBP, 512, 512, 0L, 0L, 0L, 0, 512);
  // score path: exact dtype (top-k stability)
  gemm_f32bf_kernel<<<dim3(64, 1, 1), 256, 0, stream>>>(x, key_w, KL, key_b, FLAG, 512, 512, 64, 64, 0L, 0L, 0L);
  gemm_f32bf_kernel<<<dim3(64, 1, 8), 256, 0, stream>>>(hs, query_w, QL, nullptr, FLAG, 512, 4096, 64, 512, 512L, 32768L, 64L);
  select_kernel<<<4096, 256, 0, stream>>>(QL, KL, key_b, value_b, VL, FLAG, MASK, INP);

  // ---- GRU: 8-phase GEMMs (T1+T2+fa-reuse), adaptive chunking ----
  const size_t base_g = OFF_R + 33554432UL;   // after INP [8][4096][512]
  int MCG = 4096;
  if (ws_size < base_g + 2UL * 8 * 4096 * 1536 * 2) MCG = 2048;
  if (ws_size < base_g + 2UL * 8 * 2048 * 1536 * 2) MCG = 1024;
  u16* GI = (u16*)(ws + base_g);
  u16* GH = GI + (size_t)8 * MCG * 1536;
  for (int c = 0; c < 4096 / MCG; ++c) {
    gemm8_kernel<1, 1><<<dim3(MCG / 256, 6, 8), 512, 0, stream>>>(
        INP + (size_t)c * MCG * 512, WIH, GI, BIH, 512, 2097152L, 786432L, (long)MCG * 1536, 1536, 1536);
    gemm8_kernel<1, 0><<<dim3(MCG / 256, 6, 8), 512, 0, stream>>>(
        HSB + (size_t)c * MCG * 4096, WHH, GH, nullptr, 4096, 512L, 786432L, (long)MCG * 1536, 0, 1536);
    gates_kernel<<<dim3(MCG, 8), 128, 0, stream>>>(GI, GH, HSB, HMF, BHH, RNG, RNB, FLAG, c * MCG, d_out, HB);
  }

  // ---- communication attention: 8-phase GEMMs, adaptive chunking ----
  int MCC = 4096;
  if (ws_size < OFF_R + (size_t)8 * 4096 * (768 + 512 + 512) * 2) MCC = 2048;
  u16* QVC  = (u16*)(ws + OFF_R);
  u16* CTX  = QVC + (size_t)8 * MCC * 768;
  u16* CTX2 = CTX + (size_t)8 * MCC * 512;
  for (int d2 = 0; d2 < 4096 / MCC; ++d2) {
    gemm8_kernel<1, 0><<<dim3(MCC / 256, 3, 8), 512, 0, stream>>>(
        HB + (size_t)d2 * MCC * 512, QVW, QVC, nullptr, 512, 2097152L, 393216L, (long)MCC * 768, 0, 768);
    attn_kernel<<<dim3(MCC), 256, 0, stream>>>(QVC, MASK, d2 * MCC, CTX);
    gemm8_kernel<1, 0><<<dim3(MCC / 256, 2, 8), 512, 0, stream>>>(
        CTX, OUTW, CTX2, nullptr, 512, (long)MCC * 512, 262144L, (long)MCC * 512, 0, 512);
    final_kernel<<<dim3(MCC, 8), 128, 0, stream>>>(CTX2, HB, HSB, MASK, LNG, LNB, FLAG, d2 * MCC, d_out);
  }
  (void)in_sizes; (void)n_in; (void)out_size; (void)ws_size;
}

// Round 12
// 516.054 us; speedup vs baseline: 1.0471x; 1.0019x over previous
//
#include <hip/hip_runtime.h>

typedef __attribute__((ext_vector_type(4))) float f32x4;
typedef __attribute__((ext_vector_type(8))) short bf16x8;
typedef unsigned short u16;

#define DEVINL static __device__ __forceinline__

DEVINL float b2f(u16 u) { union { unsigned int i; float f; } x; x.i = ((unsigned int)u) << 16; return x.f; }
DEVINL u16 f2bf(float f) {
  union { float f; unsigned int i; } x; x.f = f;
  unsigned int r = x.i + 0x7fffu + ((x.i >> 16) & 1u);
  return (u16)(r >> 16);
}
DEVINL float ldin(const void* p, long i, int f) {
  return f ? ((const float*)p)[i] : b2f(((const u16*)p)[i]);
}
DEVINL void ld4bf(const u16* p, float* o) {
  ushort4 v = *(const ushort4*)p;
  o[0] = b2f(v.x); o[1] = b2f(v.y); o[2] = b2f(v.z); o[3] = b2f(v.w);
}
DEVINL void st4out(void* out, size_t idx, const float* v, int f) {
  if (f) {
    float4 t; t.x = v[0]; t.y = v[1]; t.z = v[2]; t.w = v[3];
    *(float4*)((float*)out + idx) = t;
  } else {
    ushort4 t; t.x = f2bf(v[0]); t.y = f2bf(v[1]); t.z = f2bf(v[2]); t.w = f2bf(v[3]);
    *(ushort4*)((u16*)out + idx) = t;
  }
}
DEVINL void cv8(const void* s, long i, int f, u16* d) {
  if (f) {
    const float4 a = *(const float4*)((const float*)s + i);
    const float4 b = *(const float4*)((const float*)s + i + 4);
    ushort4 lo, hi;
    lo.x = f2bf(a.x); lo.y = f2bf(a.y); lo.z = f2bf(a.z); lo.w = f2bf(a.w);
    hi.x = f2bf(b.x); hi.y = f2bf(b.y); hi.z = f2bf(b.z); hi.w = f2bf(b.w);
    *(ushort4*)d = lo; *(ushort4*)(d + 4) = hi;
  } else {
    const ushort4 a = *(const ushort4*)((const u16*)s + i);
    const ushort4 b = *(const ushort4*)((const u16*)s + i + 4);
    *(ushort4*)d = a; *(ushort4*)(d + 4) = b;
  }
}

// ---------------- workspace layout (bytes); all GEMM K padded to 512 ----------------
static constexpr size_t OFF_FLAG = 0;
static constexpr size_t OFF_WIH  = 1024;        // bf16 [8][1536][512] (k>=400 zero)
static constexpr size_t OFF_WHH  = 12583936;    // bf16 [8][1536][512]
static constexpr size_t OFF_QVW  = 25166848;    // bf16 [8][768][512]
static constexpr size_t OFF_OUTW = 31458304;    // bf16 [8][512][512] (k>=400 zero)
static constexpr size_t OFF_VALW = 35652608;    // bf16 [512][512]
static constexpr size_t OFF_VBP  = 36176896;    // bf16 [512]
static constexpr size_t OFF_BIH  = 36177920;    // bf16 [8][1536]
static constexpr size_t OFF_BHH  = 36202496;    // bf16 [8][1536]
static constexpr size_t OFF_RNG  = 36227072;    // bf16 [8][512]
static constexpr size_t OFF_RNB  = 36235264;    // bf16 [8][512]
static constexpr size_t OFF_LNG  = 36243456;    // bf16 [512]
static constexpr size_t OFF_LNB  = 36244480;    // bf16 [512]
static constexpr size_t OFF_HMF  = 36245504;    // f32  [4096]
static constexpr size_t OFF_XB   = 36261888;    // bf16 [4096][512]
static constexpr size_t OFF_HSB  = 40456192;    // bf16 [4096][8][512] (straight hs copy)
static constexpr size_t OFF_KL   = 74010624;    // f32  [4096][64]
static constexpr size_t OFF_VL   = 75059200;    // f32  [4096][512]
static constexpr size_t OFF_QL   = 83447808;    // f32  [4096][512]
static constexpr size_t OFF_MASK = 91836416;    // f32  [4096][8]
static constexpr size_t OFF_HB   = 91967488;    // bf16 [8][4096][512]
static constexpr size_t OFF_R    = 125521920;   // reusable: INP[8][4096][512] + GI/GH | QVC/CTX/CTX2

// ---------------- dtype detect: even-u16 plausibility ----------------
__global__ __launch_bounds__(256) void detect_kernel(const u16* __restrict__ hs_u, int* __restrict__ flag) {
  __shared__ int cnt;
  if (threadIdx.x == 0) cnt = 0;
  __syncthreads();
  int ok = 0;
  for (int i = threadIdx.x; i < 1024; i += 256) {
    const float v = fabsf(b2f(hs_u[2 * i]));
    if (v > 9.094947e-13f && v < 1.0995116e12f) ok++;   // 2^-40 .. 2^40
  }
  atomicAdd(&cnt, ok);
  __syncthreads();
  if (threadIdx.x == 0) flag[0] = (cnt >= 921) ? 0 : 1;  // bf16(0) / fp32(1)
}

// ---------------- vectorized flat convert/pad (8 elems/thread) ----------------
__global__ __launch_bounds__(256) void flatconv_kernel(
    const void* __restrict__ W_ih, const void* __restrict__ W_hh, const void* __restrict__ x,
    const void* __restrict__ hs, const void* __restrict__ value_b, const void* __restrict__ b_ih,
    const void* __restrict__ b_hh, const void* __restrict__ rnn_g, const void* __restrict__ rnn_b,
    const void* __restrict__ ln_g, const void* __restrict__ ln_b, const void* __restrict__ h_masks,
    const int* __restrict__ flagp,
    u16* __restrict__ WIH, u16* __restrict__ WHH, u16* __restrict__ XB, u16* __restrict__ HSB,
    u16* __restrict__ VBP, u16* __restrict__ BIH, u16* __restrict__ BHH,
    u16* __restrict__ RNG, u16* __restrict__ RNB, u16* __restrict__ LNG, u16* __restrict__ LNB,
    float* __restrict__ HMF)
{
  const int f = flagp[0];
  long t = (long)blockIdx.x * 256 + threadIdx.x;
  if (t < 786432L) {                         // WIH [r=u*1536][512], pad k>=400
    const long r = t >> 6; const int k = (int)(t & 63) * 8;
    u16* d = WIH + r * 512 + k;
    if (k < 400) cv8(W_ih, r * 400 + k, f, d);
    else { ushort4 z{0,0,0,0}; *(ushort4*)d = z; *(ushort4*)(d + 4) = z; }
    return;
  }
  t -= 786432L;
  if (t < 786432L) { cv8(W_hh, t * 8, f, WHH + t * 8); return; }
  t -= 786432L;
  if (t < 262144L) { cv8(x, t * 8, f, XB + t * 8); return; }
  t -= 262144L;
  if (t < 2097152L) { cv8(hs, t * 8, f, HSB + t * 8); return; }
  t -= 2097152L;
  if (t < 512L) { VBP[t] = (t < 400) ? f2bf(ldin(value_b, t, f)) : (u16)0; return; }
  t -= 512L;
  if (t < 12288L) { BIH[t] = f2bf(ldin(b_ih, t, f)); return; }
  t -= 12288L;
  if (t < 12288L) { BHH[t] = f2bf(ldin(b_hh, t, f)); return; }
  t -= 12288L;
  if (t < 4096L) { RNG[t] = f2bf(ldin(rnn_g, t, f)); return; }
  t -= 4096L;
  if (t < 4096L) { RNB[t] = f2bf(ldin(rnn_b, t, f)); return; }
  t -= 4096L;
  if (t < 512L) { LNG[t] = f2bf(ldin(ln_g, t, f)); return; }
  t -= 512L;
  if (t < 512L) { LNB[t] = f2bf(ldin(ln_b, t, f)); return; }
  t -= 512L;
  if (t < 4096L) { HMF[t] = ldin(h_masks, t, f); return; }
}

// ---------------- LDS-tiled transpose: dst[z][n][k](bf16,[*][Kp]) = src[z][k][n], zero-pad ----------------
__global__ __launch_bounds__(256) void transpose_kernel(
    const void* __restrict__ src, const int* __restrict__ flagp, u16* __restrict__ dst,
    int K, int N, int Kp, long srcZ, long dstZ)
{
  const int f = flagp[0];
  __shared__ float t[64][65];
  const int k0 = blockIdx.x * 64, n0 = blockIdx.y * 64, z = blockIdx.z;
  const int tid = threadIdx.x;
  const int lk = tid >> 4;
  const int ln4 = (tid & 15) * 4;
#pragma unroll
  for (int p = 0; p < 4; ++p) {
    const int k = k0 + lk + p * 16;
    float v[4] = {0.f, 0.f, 0.f, 0.f};
    if (k < K) {
      const long base = srcZ * z + (long)k * N + n0 + ln4;
#pragma unroll
      for (int j = 0; j < 4; ++j)
        if (n0 + ln4 + j < N) v[j] = ldin(src, base + j, f);
    }
    t[lk + p * 16][ln4 + 0] = v[0]; t[lk + p * 16][ln4 + 1] = v[1];
    t[lk + p * 16][ln4 + 2] = v[2]; t[lk + p * 16][ln4 + 3] = v[3];
  }
  __syncthreads();
#pragma unroll
  for (int p = 0; p < 4; ++p) {
    const int n = n0 + lk + p * 16;
    ushort4 o;
    o.x = f2bf(t[ln4 + 0][lk + p * 16]);
    o.y = f2bf(t[ln4 + 1][lk + p * 16]);
    o.z = f2bf(t[ln4 + 2][lk + p * 16]);
    o.w = f2bf(t[ln4 + 3][lk + p * 16]);
    *(ushort4*)&dst[dstZ * z + (long)n * Kp + k0 + ln4] = o;
  }
}

// ---------------- 8-phase 256x256 MFMA NT GEMM, K=512 (T1+T2+T3+T4+T5, fa-reuse) ----------------
// Best measured configuration (round 9/11). Epilogue bias hoisted per-nf (FP order unchanged).
template<int OUT_BF16, int HAS_BIAS>
__global__ __launch_bounds__(512, 2) void gemm8_kernel(
    const u16* __restrict__ A, const u16* __restrict__ W, void* __restrict__ Cp,
    const u16* __restrict__ bias, int ldaE, long Az, long Wz, long Cz, int Bz, int ldc)
{
  __shared__ u16 lds[65536];   // 128 KiB
  const int tid = threadIdx.x;
  const int w = tid >> 6, l = tid & 63;
  const int wr = w >> 2, wc = w & 3;
  const int lr = l & 15, kg = l >> 4;
  const int l3 = l >> 3;
  const int l7ks = ((l & 7) ^ l3) * 8;       // T2 inverse-swizzled source col (elems)
  const int lswz = (lr & 7) << 3;            // T2 read swizzle (elems)

  // T1: bijective XCD swizzle (requires nwg % 8 == 0), by-fastest for A-panel L2 reuse
  int bx, by, bz;
  {
    const int gx = gridDim.x, gy = gridDim.y;
    const int nwg = gx * gy * (int)gridDim.z;
    int flat = (int)blockIdx.x + gx * ((int)blockIdx.y + gy * (int)blockIdx.z);
    flat = (flat & 7) * (nwg >> 3) + (flat >> 3);
    by = flat % gy; const int tmp = flat / gy;
    bx = tmp % gx; bz = tmp / gx;
  }
  const int m0 = bx * 256, n0 = by * 256, z = bz;
  const u16* Au = A + (size_t)z * Az;
  const u16* Wu = W + (size_t)z * Wz;

  f32x4 acc[8][4];
#pragma unroll
  for (int i = 0; i < 8; ++i)
#pragma unroll
    for (int j = 0; j < 4; ++j) acc[i][j] = (f32x4){0.f, 0.f, 0.f, 0.f};

  bf16x8 fa[2][4], fb[2][2];

#define GL8(srcp, dstoff) __builtin_amdgcn_global_load_lds( \
    (const __attribute__((address_space(1))) void*)(srcp), \
    (__attribute__((address_space(3))) void*)((char*)lds + 2 * (dstoff)), 16, 0, 0)

#define STAGE_A8(t, mh, slot) do { \
  _Pragma("unroll") for (int c_ = 0; c_ < 2; ++c_) { \
    const int row0_ = (mh) * 64 + w * 8 + c_ * 128; \
    GL8(Au + (size_t)(m0 + row0_ + l3) * ldaE + (t) * 64 + l7ks, (slot) * 16384 + row0_ * 64); \
  } } while (0)

#define STAGE_B8(t, nh, slot) do { \
  _Pragma("unroll") for (int c_ = 0; c_ < 2; ++c_) { \
    const int rq0_ = w * 8 + c_ * 64; \
    const int row0_ = ((rq0_ >> 5) << 6) + (nh) * 32 + (rq0_ & 31); \
    GL8(Wu + (size_t)(n0 + row0_ + l3) * 512 + (t) * 64 + l7ks, 32768 + (slot) * 16384 + row0_ * 64); \
  } } while (0)

#define VMW4 asm volatile("s_waitcnt vmcnt(4)" ::: "memory")

#define LOAD_FA(sl, mh) do { \
  _Pragma("unroll") for (int kk = 0; kk < 2; ++kk) \
    _Pragma("unroll") for (int mq = 0; mq < 4; ++mq) \
      fa[kk][mq] = *(const bf16x8*)&lds[(sl) * 16384 + (wr * 128 + (mh) * 64 + mq * 16 + lr) * 64 + ((kk * 32 + kg * 8) ^ lswz)]; \
} while (0)

#define LOAD_FB(sl, nh) do { \
  _Pragma("unroll") for (int kk = 0; kk < 2; ++kk) \
    _Pragma("unroll") for (int nq = 0; nq < 2; ++nq) \
      fb[kk][nq] = *(const bf16x8*)&lds[32768 + (sl) * 16384 + (wc * 64 + (nh) * 32 + nq * 16 + lr) * 64 + ((kk * 32 + kg * 8) ^ lswz)]; \
} while (0)

#define PHASE_MM(mh, nh, STG, VMW) do { \
  STG; \
  asm volatile("" ::: "memory"); \
  __builtin_amdgcn_s_barrier(); \
  __builtin_amdgcn_s_setprio(1); \
  _Pragma("unroll") for (int kk = 0; kk < 2; ++kk) \
    _Pragma("unroll") for (int mq = 0; mq < 4; ++mq) \
      _Pragma("unroll") for (int nq = 0; nq < 2; ++nq) \
        acc[(mh) * 4 + mq][(nh) * 2 + nq] = __builtin_amdgcn_mfma_f32_16x16x32_bf16( \
            fa[kk][mq], fb[kk][nq], acc[(mh) * 4 + mq][(nh) * 2 + nq], 0, 0, 0); \
  __builtin_amdgcn_s_setprio(0); \
  VMW; \
  asm volatile("" ::: "memory"); \
  __builtin_amdgcn_s_barrier(); \
} while (0)

  // prologue: slot0 full (tile 0) + slot1 A0,B0 (tile 1); keep slot1's 4 in flight
  STAGE_A8(0, 0, 0); STAGE_A8(0, 1, 0); STAGE_B8(0, 0, 0); STAGE_B8(0, 1, 0);
  STAGE_A8(1, 0, 1); STAGE_B8(1, 0, 1);
  asm volatile("s_waitcnt vmcnt(4)" ::: "memory");
  __builtin_amdgcn_s_barrier();

  for (int i = 0; i < 4; ++i) {
    const int tB = 2 * i + 1, tC = (2 * i + 2) & 7, tD = (2 * i + 3) & 7;
    LOAD_FA(0, 0); LOAD_FB(0, 0);
    PHASE_MM(0, 0, STAGE_A8(tB, 1, 1), );
    LOAD_FB(0, 1);
    PHASE_MM(0, 1, STAGE_B8(tB, 1, 1), );
    LOAD_FA(0, 1); LOAD_FB(0, 0);
    PHASE_MM(1, 0, STAGE_A8(tC, 0, 0), );
    LOAD_FB(0, 1);
    PHASE_MM(1, 1, STAGE_B8(tC, 0, 0), VMW4);
    LOAD_FA(1, 0); LOAD_FB(1, 0);
    PHASE_MM(0, 0, STAGE_A8(tC, 1, 0), );
    LOAD_FB(1, 1);
    PHASE_MM(0, 1, STAGE_B8(tC, 1, 0), );
    LOAD_FA(1, 1); LOAD_FB(1, 0);
    PHASE_MM(1, 0, STAGE_A8(tD, 0, 1), );
    LOAD_FB(1, 1);
    PHASE_MM(1, 1, STAGE_B8(tD, 0, 1), VMW4);
  }
  asm volatile("s_waitcnt vmcnt(0)" ::: "memory");

  float bvs[4];
#pragma unroll
  for (int nf = 0; nf < 4; ++nf)
    bvs[nf] = HAS_BIAS ? b2f(bias[(size_t)z * Bz + n0 + wc * 64 + nf * 16 + lr]) : 0.f;
  float* Cf = (float*)Cp;
  u16* Cb = (u16*)Cp;
#pragma unroll
  for (int mf = 0; mf < 8; ++mf) {
#pragma unroll
    for (int nf = 0; nf < 4; ++nf) {
      const int gc = n0 + wc * 64 + nf * 16 + lr;
#pragma unroll
      for (int t = 0; t < 4; ++t) {
        const int gr = m0 + wr * 128 + mf * 16 + kg * 4 + t;   // C/D: col=lane&15, row=(lane>>4)*4+reg
        const float v = acc[mf][nf][t] + bvs[nf];
        const size_t idx = (size_t)z * Cz + (size_t)gr * ldc + gc;
        if (OUT_BF16) Cb[idx] = f2bf(v); else Cf[idx] = v;
      }
    }
  }
#undef GL8
#undef STAGE_A8
#undef STAGE_B8
#undef VMW4
#undef LOAD_FA
#undef LOAD_FB
#undef PHASE_MM
}

// ---------------- 128x128 MFMA NT GEMM (verified; kept for VL) ----------------
template<int OUT_BF16, int HAS_BIAS>
__global__ __launch_bounds__(256) void gemm_bt_kernel(
    const u16* __restrict__ A, const u16* __restrict__ W, void* __restrict__ Cp,
    const u16* __restrict__ bias, int KP, int ldaE, long Az, long Wz, long Cz, int Bz, int ldc)
{
  __shared__ u16 lA[128 * 64];
  __shared__ u16 lB[128 * 64];
  const int tid = threadIdx.x;
  const int m0 = blockIdx.x * 128, n0 = blockIdx.y * 128, z = blockIdx.z;
  const u16* Au = A + (size_t)z * Az;
  const u16* Wu = W + (size_t)z * Wz;
  const int l = tid & 63, w = tid >> 6;
  const int WM = (w >> 1) * 64, WN = (w & 1) * 64;
  const int lr = l & 15, kg = l >> 4;
  f32x4 acc[4][4];
#pragma unroll
  for (int i = 0; i < 4; ++i)
#pragma unroll
    for (int j = 0; j < 4; ++j) acc[i][j] = (f32x4){0.f, 0.f, 0.f, 0.f};
  const int rowA = tid >> 3;
  const int cb = (tid & 7) * 16;
  const size_t rowBytesA = (size_t)ldaE * 2;
  const size_t rowBytesW = (size_t)KP * 2;
  for (int k0 = 0; k0 < KP; k0 += 64) {
    __syncthreads();
    const char* gA = (const char*)Au + (size_t)(m0 + rowA) * rowBytesA + (size_t)k0 * 2 + cb;
    const char* gB = (const char*)Wu + (size_t)(n0 + rowA) * rowBytesW + (size_t)k0 * 2 + cb;
    char* sA = (char*)lA + (w << 10);
    char* sB = (char*)lB + (w << 10);
#pragma unroll
    for (int c = 0; c < 4; ++c) {
      __builtin_amdgcn_global_load_lds(
          (const __attribute__((address_space(1))) void*)(gA + (size_t)c * 32 * rowBytesA),
          (__attribute__((address_space(3))) void*)(sA + c * 4096), 16, 0, 0);
      __builtin_amdgcn_global_load_lds(
          (const __attribute__((address_space(1))) void*)(gB + (size_t)c * 32 * rowBytesW),
          (__attribute__((address_space(3))) void*)(sB + c * 4096), 16, 0, 0);
    }
    __syncthreads();
#pragma unroll
    for (int kk = 0; kk < 64; kk += 32) {
      bf16x8 af[4], bw[4];
#pragma unroll
      for (int i = 0; i < 4; ++i)
        af[i] = *(const bf16x8*)&lA[(WM + i * 16 + lr) * 64 + kk + kg * 8];
#pragma unroll
      for (int j = 0; j < 4; ++j)
        bw[j] = *(const bf16x8*)&lB[(WN + j * 16 + lr) * 64 + kk + kg * 8];
#pragma unroll
      for (int i = 0; i < 4; ++i)
#pragma unroll
        for (int j = 0; j < 4; ++j)
          acc[i][j] = __builtin_amdgcn_mfma_f32_16x16x32_bf16(af[i], bw[j], acc[i][j], 0, 0, 0);
    }
  }
  float* Cf = (float*)Cp;
  u16* Cb = (u16*)Cp;
#pragma unroll
  for (int i = 0; i < 4; ++i) {
#pragma unroll
    for (int j = 0; j < 4; ++j) {
      const int gc = n0 + WN + j * 16 + lr;
      float bv = 0.f;
      if (HAS_BIAS) bv = b2f(bias[(size_t)z * Bz + gc]);
#pragma unroll
      for (int t = 0; t < 4; ++t) {
        const int gr = m0 + WM + i * 16 + kg * 4 + t;
        const float v = acc[i][j][t] + bv;
        const size_t idx = (size_t)z * Cz + (size_t)gr * ldc + gc;
        if (OUT_BF16) Cb[idx] = f2bf(v); else Cf[idx] = v;
      }
    }
  }
}

// ---------------- exact-dtype fp32 GEMM for the score path ----------------
__global__ __launch_bounds__(256) void gemm_f32bf_kernel(
    const void* __restrict__ A, const void* __restrict__ W, float* __restrict__ C,
    const void* __restrict__ bias, const int* __restrict__ flagp,
    int K, int lda, int ldw, int ldc, long Az, long Wz, long Cz)
{
  const int f32 = flagp[0];
  __shared__ float sA[16][65];
  __shared__ float sW[16][64];
  const int tid = threadIdx.x;
  const int m0 = blockIdx.x * 64, n0 = blockIdx.y * 64, z = blockIdx.z;
  const int tx = tid & 15, ty = tid >> 4;
  const int ar = tid >> 2, ak = (tid & 3) * 4;
  const int wk = tid >> 4, wc = (tid & 15) * 4;
  const size_t abase = (size_t)z * Az, wbase = (size_t)z * Wz;
  float acc[4][4] = {};
  for (int k0 = 0; k0 < K; k0 += 16) {
    __syncthreads();
    float a0, a1, a2, a3, w0, w1, w2, w3;
    const size_t ai = abase + (size_t)(m0 + ar) * lda + k0 + ak;
    const size_t wi = wbase + (size_t)(k0 + wk) * ldw + n0 + wc;
    if (f32) {
      const float4 av = *(const float4*)((const float*)A + ai);
      const float4 wv = *(const float4*)((const float*)W + wi);
      a0 = av.x; a1 = av.y; a2 = av.z; a3 = av.w;
      w0 = wv.x; w1 = wv.y; w2 = wv.z; w3 = wv.w;
    } else {
      const ushort4 av = *(const ushort4*)((const u16*)A + ai);
      const ushort4 wv = *(const ushort4*)((const u16*)W + wi);
      a0 = b2f(av.x); a1 = b2f(av.y); a2 = b2f(av.z); a3 = b2f(av.w);
      w0 = b2f(wv.x); w1 = b2f(wv.y); w2 = b2f(wv.z); w3 = b2f(wv.w);
    }
    sA[ak + 0][ar] = a0; sA[ak + 1][ar] = a1; sA[ak + 2][ar] = a2; sA[ak + 3][ar] = a3;
    sW[wk][wc] = w0; sW[wk][wc + 1] = w1; sW[wk][wc + 2] = w2; sW[wk][wc + 3] = w3;
    __syncthreads();
#pragma unroll
    for (int kk = 0; kk < 16; ++kk) {
      const float a0c = sA[kk][ty * 4 + 0], a1c = sA[kk][ty * 4 + 1];
      const float a2c = sA[kk][ty * 4 + 2], a3c = sA[kk][ty * 4 + 3];
      const float4 bv = *(const float4*)&sW[kk][tx * 4];
      acc[0][0] += a0c * bv.x; acc[0][1] += a0c * bv.y; acc[0][2] += a0c * bv.z; acc[0][3] += a0c * bv.w;
      acc[1][0] += a1c * bv.x; acc[1][1] += a1c * bv.y; acc[1][2] += a1c * bv.z; acc[1][3] += a1c * bv.w;
      acc[2][0] += a2c * bv.x; acc[2][1] += a2c * bv.y; acc[2][2] += a2c * bv.z; acc[2][3] += a2c * bv.w;
      acc[3][0] += a3c * bv.x; acc[3][1] += a3c * bv.y; acc[3][2] += a3c * bv.z; acc[3][3] += a3c * bv.w;
    }
  }
#pragma unroll
  for (int i = 0; i < 4; ++i)
#pragma unroll
    for (int j = 0; j < 4; ++j) {
      const int n = n0 + tx * 4 + j;
      float v = acc[i][j];
      if (bias) v += ldin(bias, n, f32);
      C[(size_t)z * Cz + (size_t)(m0 + ty * 4 + i) * ldc + n] = v;
    }
}

// ---------------- scores / top-k / probs -> mask, inp ([u][4096][512], pad>=400 zero) ----------------
__global__ __launch_bounds__(256) void select_kernel(
    const float* __restrict__ q_l, const float* __restrict__ k_l,
    const void* __restrict__ key_b, const void* __restrict__ value_b,
    const float* __restrict__ v_l, const int* __restrict__ flagp,
    float* __restrict__ mask_out, u16* __restrict__ inp)
{
  const int b = blockIdx.x, tid = threadIdx.x;
  const int f32 = flagp[0];
  __shared__ float s_sc[16], s_pm[8], s_pm1[8];
  __shared__ float s_v[400], s_vb[400];
  const int task = tid >> 4, l16 = tid & 15, uu = task & 7;
  const float* qv = q_l + (size_t)b * 512 + uu * 64;
  float p = 0.f;
  if (task < 8) {
    const float* kv = k_l + (size_t)b * 64;
    for (int k = l16; k < 64; k += 16) p += qv[k] * kv[k];
  } else {
    for (int k = l16; k < 64; k += 16) p += qv[k] * ldin(key_b, k, f32);
  }
  p += __shfl_xor(p, 8, 16); p += __shfl_xor(p, 4, 16);
  p += __shfl_xor(p, 2, 16); p += __shfl_xor(p, 1, 16);
  if (l16 == 0) s_sc[task] = p * 0.125f;
  for (int i = tid; i < 400; i += 256) { s_v[i] = v_l[(size_t)b * 512 + i]; s_vb[i] = ldin(value_b, i, f32); }
  __syncthreads();
  if (tid < 8) {
    const float s0 = s_sc[tid];
    int rank = 0;
    for (int u2 = 0; u2 < 8; ++u2) {
      const float o = s_sc[u2];
      rank += (o > s0) || (o == s0 && u2 < tid);
    }
    const float m = (rank < 5) ? 1.f : 0.f;
    mask_out[(size_t)b * 8 + tid] = m;
    const float s1 = s_sc[8 + tid];
    const float mx = fmaxf(s0, s1);
    const float e0 = expf(s0 - mx), e1 = expf(s1 - mx);
    const float p0 = e0 / (e0 + e1);
    s_pm[tid] = m * p0; s_pm1[tid] = m * (1.f - p0);
  }
  __syncthreads();
#pragma unroll
  for (int u = 0; u < 8; ++u) {
    const float pm = s_pm[u], pm1 = s_pm1[u];
    for (int i = tid; i < 512; i += 256) {
      const float v = (i < 400) ? (pm * s_v[i] + pm1 * s_vb[i]) : 0.f;
      inp[((size_t)u * 4096 + b) * 512 + i] = f2bf(v);
    }
  }
}

// ---------------- shared 2-value block reduction (128 threads) ----------------
__device__ __forceinline__ void block_reduce_2(float& a, float& b) {
#pragma unroll
  for (int o = 32; o; o >>= 1) { a += __shfl_down(a, o, 64); b += __shfl_down(b, o, 64); }
  __shared__ float red[4];
  const int tid = threadIdx.x;
  if ((tid & 63) == 0) { red[(tid >> 6) * 2] = a; red[(tid >> 6) * 2 + 1] = b; }
  __syncthreads();
  a = red[0] + red[2]; b = red[1] + red[3];
}

// ---------------- GRU gates + per-unit LN -> out0, hb (grid = [MCG, 8]) ----------------
__global__ __launch_bounds__(128) void gates_kernel(
    const u16* __restrict__ gi, const u16* __restrict__ gh,
    const u16* __restrict__ hsb, const float* __restrict__ hmf,
    const u16* __restrict__ bhh, const u16* __restrict__ rng, const u16* __restrict__ rnb,
    const int* __restrict__ flagp, int bbase, void* __restrict__ out0, u16* __restrict__ hb)
{
  const int f = flagp[0];
  const int u = blockIdx.y, bl = blockIdx.x;
  const int b = bbase + bl;
  const int h0 = threadIdx.x * 4;
  const size_t rowg = ((size_t)u * gridDim.x + bl) * 1536;
  const size_t rowhs = ((size_t)b * 8 + u) * 512;
  const size_t rowhb = ((size_t)u * 4096 + b) * 512;
  float ir[4], iz[4], inn[4], hr[4], hz[4], hnn[4], hsv[4], br[4], bz[4], bn[4];
  ld4bf(gi + rowg + h0, ir);
  ld4bf(gi + rowg + 512 + h0, iz);
  ld4bf(gi + rowg + 1024 + h0, inn);
  ld4bf(gh + rowg + h0, hr);
  ld4bf(gh + rowg + 512 + h0, hz);
  ld4bf(gh + rowg + 1024 + h0, hnn);
  ld4bf(hsb + rowhs + h0, hsv);
  ld4bf(bhh + u * 1536 + h0, br);
  ld4bf(bhh + u * 1536 + 512 + h0, bz);
  ld4bf(bhh + u * 1536 + 1024 + h0, bn);
  const float hmask = hmf[b];
  float hn[4]; float sum = 0.f, sq = 0.f;
#pragma unroll
  for (int j = 0; j < 4; ++j) {
    const float hrf = hmask * hr[j] + br[j];
    const float hzf = hmask * hz[j] + bz[j];
    const float hnf = hmask * hnn[j] + bn[j];
    const float r = 1.f / (1.f + expf(-(ir[j] + hrf)));
    const float zz = 1.f / (1.f + expf(-(iz[j] + hzf)));
    const float n = tanhf(inn[j] + r * hnf);
    const float hmv = hsv[j] * hmask;
    const float h = (1.f - zz) * n + zz * hmv;
    hn[j] = h; sum += h; sq += h * h;
  }
  block_reduce_2(sum, sq);
  const float mean = sum * (1.f / 512.f);
  const float var = fmaxf(sq * (1.f / 512.f) - mean * mean, 0.f);
  const float rstd = rsqrtf(var + 1e-5f);
  float gg[4], bb[4];
  ld4bf(rng + u * 512 + h0, gg);
  ld4bf(rnb + u * 512 + h0, bb);
  float yv[4];
#pragma unroll
  for (int j = 0; j < 4; ++j) yv[j] = (hn[j] - mean) * rstd * gg[j] + bb[j];
  st4out(out0, (size_t)b * 4096 + u * 512 + h0, yv, f);
  ushort4 hv;
  hv.x = f2bf(hn[0]); hv.y = f2bf(hn[1]); hv.z = f2bf(hn[2]); hv.w = f2bf(hn[3]);
  *(ushort4*)(hb + rowhb + h0) = hv;
}

// ---------------- per-b 8x8 inter-unit attention -> ctx [u][MC][512] (pad>=400 zero) ----------------
__global__ __launch_bounds__(256) void attn_kernel(
    const u16* __restrict__ qvc, const float* __restrict__ maskp, int bbase,
    u16* __restrict__ ctx)
{
  const int bl = blockIdx.x, tid = threadIdx.x;
  const int b = bbase + bl;
  const size_t MC = gridDim.x;
  __shared__ float s_q[8][128], s_k[8][128];
  __shared__ float s_ap[4][8][8];
  __shared__ float s_v[8][400];
  for (int i = tid; i < 1024; i += 256) {
    const int u = i >> 7, c = i & 127;
    const size_t base = ((size_t)u * MC + bl) * 768;
    s_q[u][c] = b2f(qvc[base + c]);
    s_k[u][c] = b2f(qvc[base + 128 + c]);
  }
  for (int i = tid; i < 3200; i += 256) {
    const int u = i / 400, c = i - u * 400;
    s_v[u][c] = b2f(qvc[((size_t)u * MC + bl) * 768 + 256 + c]);
  }
  __syncthreads();
  const int n = tid >> 6, uu = (tid >> 3) & 7, vv = tid & 7;
  float a = 0.f;
#pragma unroll
  for (int k = 0; k < 32; ++k) a += s_q[uu][n * 32 + k] * s_k[vv][n * 32 + k];
  a *= 0.17677669529663687f;
  float mx = a;
  for (int o = 4; o; o >>= 1) mx = fmaxf(mx, __shfl_xor(mx, o, 8));
  const float e = expf(a - mx);
  float se = e;
  for (int o = 4; o; o >>= 1) se += __shfl_xor(se, o, 8);
  s_ap[n][uu][vv] = e / se * maskp[(size_t)b * 8 + uu];
  __syncthreads();
  for (int i = tid; i < 4096; i += 256) {
    const int u = i >> 9, c = i & 511;
    float v = 0.f;
    if (c < 400) {
      const int nn = c / 100;
      const float* ap = s_ap[nn][u];
#pragma unroll
      for (int v2 = 0; v2 < 8; ++v2) v += ap[v2] * s_v[v2][c];
    }
    ctx[((size_t)u * MC + bl) * 512 + c] = f2bf(v);
  }
}

// ---------------- final LN + masked blend -> out2 (grid = [MCC, 8]) ----------------
__global__ __launch_bounds__(128) void final_kernel(
    const u16* __restrict__ ctx2, const u16* __restrict__ hb, const u16* __restrict__ hsb,
    const float* __restrict__ maskp, const u16* __restrict__ lng, const u16* __restrict__ lnb,
    const int* __restrict__ flagp, int bbase, void* __restrict__ outp)
{
  const int f = flagp[0];
  const int u = blockIdx.y, bl = blockIdx.x;
  const int b = bbase + bl;
  const int h0 = threadIdx.x * 4;
  const size_t rowc = ((size_t)u * gridDim.x + bl) * 512;
  const size_t rowhs = ((size_t)b * 8 + u) * 512;
  const size_t rowhb = ((size_t)u * 4096 + b) * 512;
  float cv[4], hbv[4];
  ld4bf(ctx2 + rowc + h0, cv);
  ld4bf(hb + rowhb + h0, hbv);
  float v[4] = { cv[0] + hbv[0], cv[1] + hbv[1], cv[2] + hbv[2], cv[3] + hbv[3] };
  float sum = v[0] + v[1] + v[2] + v[3];
  float sq = v[0] * v[0] + v[1] * v[1] + v[2] * v[2] + v[3] * v[3];
  block_reduce_2(sum, sq);
  const float mean = sum * (1.f / 512.f);
  const float var = fmaxf(sq * (1.f / 512.f) - mean * mean, 0.f);
  const float rstd = rsqrtf(var + 1e-5f);
  float gg[4], bb2[4], hsv[4];
  ld4bf(lng + h0, gg); ld4bf(lnb + h0, bb2); ld4bf(hsb + rowhs + h0, hsv);
  const float msk = maskp[(size_t)b * 8 + u];
  float ov[4];
#pragma unroll
  for (int j = 0; j < 4; ++j)
    ov[j] = msk * ((v[j] - mean) * rstd * gg[j] + bb2[j]) + (1.f - msk) * hsv[j];
  st4out(outp, (size_t)16777216 + (size_t)(b * 8 + u) * 512 + h0, ov, f);
}

extern "C" void kernel_launch(void* const* d_in, const int* in_sizes, int n_in,
                              void* d_out, int out_size, void* d_ws, size_t ws_size,
                              hipStream_t stream) {
  const void* x       = d_in[0];
  const void* hs      = d_in[1];
  const void* h_masks = d_in[2];
  const void* key_w   = d_in[3];
  const void* key_b   = d_in[4];
  const void* value_w = d_in[5];
  const void* value_b = d_in[6];
  const void* query_w = d_in[7];
  const void* qc_w    = d_in[8];
  const void* kc_w    = d_in[9];
  const void* vc_w    = d_in[10];
  const void* out_w   = d_in[11];
  const void* ln_g    = d_in[12];
  const void* ln_b    = d_in[13];
  const void* W_ih    = d_in[14];
  const void* b_ih    = d_in[15];
  const void* W_hh    = d_in[16];
  const void* b_hh    = d_in[17];
  const void* rnn_g   = d_in[18];
  const void* rnn_b   = d_in[19];

  char* ws = (char*)d_ws;
  int*   FLAG = (int*)(ws + OFF_FLAG);
  u16*   WIH  = (u16*)(ws + OFF_WIH);
  u16*   WHH  = (u16*)(ws + OFF_WHH);
  u16*   QVW  = (u16*)(ws + OFF_QVW);
  u16*   OUTW = (u16*)(ws + OFF_OUTW);
  u16*   VALW = (u16*)(ws + OFF_VALW);
  u16*   VBP  = (u16*)(ws + OFF_VBP);
  u16*   BIH  = (u16*)(ws + OFF_BIH);
  u16*   BHH  = (u16*)(ws + OFF_BHH);
  u16*   RNG  = (u16*)(ws + OFF_RNG);
  u16*   RNB  = (u16*)(ws + OFF_RNB);
  u16*   LNG  = (u16*)(ws + OFF_LNG);
  u16*   LNB  = (u16*)(ws + OFF_LNB);
  float* HMF  = (float*)(ws + OFF_HMF);
  u16*   XB   = (u16*)(ws + OFF_XB);
  u16*   HSB  = (u16*)(ws + OFF_HSB);
  float* KL   = (float*)(ws + OFF_KL);
  float* VL   = (float*)(ws + OFF_VL);
  float* QL   = (float*)(ws + OFF_QL);
  float* MASK = (float*)(ws + OFF_MASK);
  u16*   HB   = (u16*)(ws + OFF_HB);
  u16*   INP  = (u16*)(ws + OFF_R);

  detect_kernel<<<1, 256, 0, stream>>>((const u16*)hs, FLAG);
  flatconv_kernel<<<15511, 256, 0, stream>>>(
      W_ih, W_hh, x, hs, value_b, b_ih, b_hh, rnn_g, rnn_b, ln_g, ln_b, h_masks, FLAG,
      WIH, WHH, XB, HSB, VBP, BIH, BHH, RNG, RNB, LNG, LNB, HMF);
  // weight transposes (dst[n][k] = src[k][n], zero-padded to Kp=512)
  transpose_kernel<<<dim3(8, 2, 8), 256, 0, stream>>>(qc_w,    FLAG, QVW,          512, 128, 512, 65536L,  393216L);
  transpose_kernel<<<dim3(8, 2, 8), 256, 0, stream>>>(kc_w,    FLAG, QVW + 65536,  512, 128, 512, 65536L,  393216L);
  transpose_kernel<<<dim3(8, 8, 8), 256, 0, stream>>>(vc_w,    FLAG, QVW + 131072, 512, 400, 512, 204800L, 393216L);
  transpose_kernel<<<dim3(8, 8, 8), 256, 0, stream>>>(out_w,   FLAG, OUTW,         400, 512, 512, 204800L, 262144L);
  transpose_kernel<<<dim3(8, 8, 1), 256, 0, stream>>>(value_w, FLAG, VALW,         512, 400, 512, 0L,      0L);
  // v_l = x @ value_w + value_b  (128^2 MFMA, f32 out)
  gemm_bt_kernel<0, 1><<<dim3(32, 4, 1), 256, 0, stream>>>(XB, VALW, VL, VBP, 512, 512, 0L, 0L, 0L, 0, 512);
  // score path: exact dtype (top-k stability)
  gemm_f32bf_kernel<<<dim3(64, 1, 1), 256, 0, stream>>>(x, key_w, KL, key_b, FLAG, 512, 512, 64, 64, 0L, 0L, 0L);
  gemm_f32bf_kernel<<<dim3(64, 1, 8), 256, 0, stream>>>(hs, query_w, QL, nullptr, FLAG, 512, 4096, 64, 512, 512L, 32768L, 64L);
  select_kernel<<<4096, 256, 0, stream>>>(QL, KL, key_b, value_b, VL, FLAG, MASK, INP);

  // ---- GRU: 8-phase GEMMs (T1+T2+fa-reuse), adaptive chunking ----
  const size_t base_g = OFF_R + 33554432UL;   // after INP [8][4096][512]
  int MCG = 4096;
  if (ws_size < base_g + 2UL * 8 * 4096 * 1536 * 2) MCG = 2048;
  if (ws_size < base_g + 2UL * 8 * 2048 * 1536 * 2) MCG = 1024;
  u16* GI = (u16*)(ws + base_g);
  u16* GH = GI + (size_t)8 * MCG * 1536;
  for (int c = 0; c < 4096 / MCG; ++c) {
    gemm8_kernel<1, 1><<<dim3(MCG / 256, 6, 8), 512, 0, stream>>>(
        INP + (size_t)c * MCG * 512, WIH, GI, BIH, 512, 2097152L, 786432L, (long)MCG * 1536, 1536, 1536);
    gemm8_kernel<1, 0><<<dim3(MCG / 256, 6, 8), 512, 0, stream>>>(
        HSB + (size_t)c * MCG * 4096, WHH, GH, nullptr, 4096, 512L, 786432L, (long)MCG * 1536, 0, 1536);
    gates_kernel<<<dim3(MCG, 8), 128, 0, stream>>>(GI, GH, HSB, HMF, BHH, RNG, RNB, FLAG, c * MCG, d_out, HB);
  }

  // ---- communication attention: 8-phase GEMMs, adaptive chunking ----
  int MCC = 4096;
  if (ws_size < OFF_R + (size_t)8 * 4096 * (768 + 512 + 512) * 2) MCC = 2048;
  u16* QVC  = (u16*)(ws + OFF_R);
  u16* CTX  = QVC + (size_t)8 * MCC * 768;
  u16* CTX2 = CTX + (size_t)8 * MCC * 512;
  for (int d2 = 0; d2 < 4096 / MCC; ++d2) {
    gemm8_kernel<1, 0><<<dim3(MCC / 256, 3, 8), 512, 0, stream>>>(
        HB + (size_t)d2 * MCC * 512, QVW, QVC, nullptr, 512, 2097152L, 393216L, (long)MCC * 768, 0, 768);
    attn_kernel<<<dim3(MCC), 256, 0, stream>>>(QVC, MASK, d2 * MCC, CTX);
    gemm8_kernel<1, 0><<<dim3(MCC / 256, 2, 8), 512, 0, stream>>>(
        CTX, OUTW, CTX2, nullptr, 512, (long)MCC * 512, 262144L, (long)MCC * 512, 0, 512);
    final_kernel<<<dim3(MCC, 8), 128, 0, stream>>>(CTX2, HB, HSB, MASK, LNG, LNB, FLAG, d2 * MCC, d_out);
  }
  (void)in_sizes; (void)n_in; (void)out_size; (void)ws_size;
}